// Round 1
// baseline (218.634 us; speedup 1.0000x reference)
//
#include <hip/hip_runtime.h>

typedef unsigned short u16;
typedef __bf16 bf16x8 __attribute__((ext_vector_type(8)));
typedef float f32x4 __attribute__((ext_vector_type(4)));

__device__ __forceinline__ u16 f2bf(float f) {
  unsigned int u = __float_as_uint(f);
  u += 0x7fffu + ((u >> 16) & 1u);
  return (u16)(u >> 16);
}

// ---- constants -------------------------------------------------------------
// B=8, C=256, H=W=64 -> L=4096, M = B*L = 32768, NHEAD=8, dim=32
#define MROWS 32768
// ws layout (bytes)
#define OFF_WQ   0u
#define OFF_WK   131072u
#define OFF_WV   262144u
#define OFF_WM   393216u
#define OFF_W1   524288u
#define OFF_W2   1048576u
#define OFF_CAT  1310720u     /* u16 [M][512]  (cols 0:256 xs_bf16, 256:512 ln1 out) */
#define OFF_SSB  34865152u    /* u16 [M][256]  ss_bf16 */
#define OFF_Q    51642368u    /* f32 [M][256]  Q=elu(q)+1 ; later reused: hidden bf16 [M][512] */
#define OFF_K    85196800u    /* f32 [M][256]  K=elu(k)+1 ; later reused: gemm2 out f32 [M][256] */
#define OFF_V    118751232u   /* f32 [M][256]  vals=v/L   ; later reused: wm out f32 [M][256] */
#define OFF_KV   152305664u   /* f32 [64][32][32] */
#define OFF_KS   152567808u   /* f32 [64][32] */
#define OFF_ATT  152576000u   /* u16 [M][256] attn out bf16 */
#define OFF_KVP  169353216u   /* f32 [8][64][32][32] partials */
#define OFF_KSP  171450368u   /* f32 [8][64][32] partials */

// ---- transpose fp32 [C,L] -> bf16 [L,C] (into dst with row stride dstride) --
__global__ __launch_bounds__(256) void transpose_in_kernel(
    const float* __restrict__ src, u16* __restrict__ dst, int dstride) {
  __shared__ float s[32][33];
  int b = blockIdx.z;
  int lt = blockIdx.x * 32, ct = blockIdx.y * 32;
  int tx = threadIdx.x & 31, ty = threadIdx.x >> 5;
#pragma unroll
  for (int i = 0; i < 4; ++i)
    s[ty + i * 8][tx] = src[((size_t)b * 256 + ct + ty + i * 8) * 4096 + lt + tx];
  __syncthreads();
#pragma unroll
  for (int i = 0; i < 4; ++i)
    dst[((size_t)b * 4096 + lt + ty + i * 8) * dstride + ct + tx] = f2bf(s[tx][ty + i * 8]);
}

// ---- weight prep: fp32 [K,N] -> bf16 [N,K] ---------------------------------
__global__ __launch_bounds__(256) void wprep_kernel(
    const float* __restrict__ src, u16* __restrict__ dst, int Kd, int Nd) {
  __shared__ float s[32][33];
  int kt = blockIdx.x * 32, nt = blockIdx.y * 32;
  int tx = threadIdx.x & 31, ty = threadIdx.x >> 5;
#pragma unroll
  for (int i = 0; i < 4; ++i)
    s[ty + i * 8][tx] = src[(size_t)(kt + ty + i * 8) * Nd + nt + tx];
  __syncthreads();
#pragma unroll
  for (int i = 0; i < 4; ++i)
    dst[(size_t)(nt + ty + i * 8) * Kd + kt + tx] = f2bf(s[tx][ty + i * 8]);
}

// ---- bf16 MFMA GEMM: out[M,N] = A[M,K] @ Wt[N,K]^T -------------------------
// 128x128 tile, 4 waves (2x2), each wave 64x64 via 4x4 frags of 16x16x32.
// EPI: 0 plain f32, 1 elu+1 f32, 2 *(1/4096) f32, 3 relu -> bf16
template <int EPI>
__global__ __launch_bounds__(256) void gemm_kernel(
    const u16* __restrict__ A, int lda, const u16* __restrict__ Wt, int K,
    void* __restrict__ outp, int ldo) {
  __shared__ alignas(16) u16 sA[128 * 64];
  __shared__ alignas(16) u16 sB[128 * 64];
  const int tid = threadIdx.x;
  const int m0 = blockIdx.y * 128, n0 = blockIdx.x * 128;
  const int w = tid >> 6, lane = tid & 63;
  const int wm = (w >> 1) * 64, wn = (w & 1) * 64;
  const int lr = lane & 15, lk = lane >> 4;
  f32x4 acc[4][4] = {};

  const int nkt = K >> 6;
  for (int kt = 0; kt < nkt; ++kt) {
    __syncthreads();
#pragma unroll
    for (int i = 0; i < 4; ++i) {
      int id = tid + i * 256;
      int row = id >> 3, ch = (id & 7) << 3;
      int sw = ch ^ ((row & 7) << 3);
      *reinterpret_cast<uint4*>(&sA[row * 64 + sw]) =
          *reinterpret_cast<const uint4*>(A + (size_t)(m0 + row) * lda + kt * 64 + ch);
      *reinterpret_cast<uint4*>(&sB[row * 64 + sw]) =
          *reinterpret_cast<const uint4*>(Wt + (size_t)(n0 + row) * K + kt * 64 + ch);
    }
    __syncthreads();
    bf16x8 af[4][2], bfr[4][2];
#pragma unroll
    for (int f = 0; f < 4; ++f) {
#pragma unroll
      for (int ks = 0; ks < 2; ++ks) {
        int ar = wm + f * 16 + lr;
        af[f][ks] = *reinterpret_cast<const bf16x8*>(
            &sA[ar * 64 + ((ks * 32 + lk * 8) ^ ((ar & 7) << 3))]);
        int br = wn + f * 16 + lr;
        bfr[f][ks] = *reinterpret_cast<const bf16x8*>(
            &sB[br * 64 + ((ks * 32 + lk * 8) ^ ((br & 7) << 3))]);
      }
    }
#pragma unroll
    for (int ks = 0; ks < 2; ++ks)
#pragma unroll
      for (int fm = 0; fm < 4; ++fm)
#pragma unroll
        for (int fn = 0; fn < 4; ++fn)
          acc[fm][fn] = __builtin_amdgcn_mfma_f32_16x16x32_bf16(
              af[fm][ks], bfr[fn][ks], acc[fm][fn], 0, 0, 0);
  }

  const int r0 = (lane >> 4) * 4, c0 = lane & 15;
#pragma unroll
  for (int fm = 0; fm < 4; ++fm) {
#pragma unroll
    for (int fn = 0; fn < 4; ++fn) {
      int gr = m0 + wm + fm * 16 + r0;
      int gc = n0 + wn + fn * 16 + c0;
#pragma unroll
      for (int r = 0; r < 4; ++r) {
        float v = acc[fm][fn][r];
        if (EPI == 1) v = v > 0.f ? v + 1.f : __expf(v);
        if (EPI == 2) v = v * (1.f / 4096.f);
        if (EPI == 3) {
          v = v > 0.f ? v : 0.f;
          ((u16*)outp)[(size_t)(gr + r) * ldo + gc] = f2bf(v);
        } else {
          ((float*)outp)[(size_t)(gr + r) * ldo + gc] = v;
        }
      }
    }
  }
}

// ---- KV partial: KVp[s,bh,d,v] = sum_{l in slice} K[l,d]*vals[l,v] ----------
__global__ __launch_bounds__(256) void kv_partial_kernel(
    const float* __restrict__ Kb, const float* __restrict__ Vb,
    float* __restrict__ KVp, float* __restrict__ KSp) {
  __shared__ alignas(16) float sK[64][32];
  __shared__ alignas(16) float sV[64][32];
  const int bh = blockIdx.x, sl = blockIdx.y;
  const int b = bh >> 3, h = bh & 7;
  const int t = threadIdx.x;
  const int lrow = t >> 2, lcol = (t & 3) * 8;
  const int d = t >> 3, vg = (t & 7) * 4;
  float a0 = 0, a1 = 0, a2 = 0, a3 = 0, ks = 0;
  for (int lt = 0; lt < 512; lt += 64) {
    __syncthreads();
    size_t roff = ((size_t)b * 4096 + sl * 512 + lt + lrow) * 256 + h * 32 + lcol;
    *reinterpret_cast<float4*>(&sK[lrow][lcol]) = *reinterpret_cast<const float4*>(Kb + roff);
    *reinterpret_cast<float4*>(&sK[lrow][lcol + 4]) = *reinterpret_cast<const float4*>(Kb + roff + 4);
    *reinterpret_cast<float4*>(&sV[lrow][lcol]) = *reinterpret_cast<const float4*>(Vb + roff);
    *reinterpret_cast<float4*>(&sV[lrow][lcol + 4]) = *reinterpret_cast<const float4*>(Vb + roff + 4);
    __syncthreads();
#pragma unroll 8
    for (int i = 0; i < 64; ++i) {
      float kd = sK[i][d];
      a0 += kd * sV[i][vg + 0];
      a1 += kd * sV[i][vg + 1];
      a2 += kd * sV[i][vg + 2];
      a3 += kd * sV[i][vg + 3];
      ks += kd;
    }
  }
  float* o = KVp + (size_t)sl * 65536 + bh * 1024 + d * 32 + vg;
  o[0] = a0; o[1] = a1; o[2] = a2; o[3] = a3;
  if ((t & 7) == 0) KSp[(size_t)sl * 2048 + bh * 32 + d] = ks;
}

__global__ __launch_bounds__(256) void kv_reduce_kernel(
    const float* __restrict__ KVp, const float* __restrict__ KSp,
    float* __restrict__ KV, float* __restrict__ Ksum) {
  int gid = blockIdx.x * 256 + threadIdx.x;
  if (gid < 65536) {
    float s = 0;
#pragma unroll
    for (int i = 0; i < 8; ++i) s += KVp[(size_t)i * 65536 + gid];
    KV[gid] = s;
  } else if (gid - 65536 < 2048) {
    int j = gid - 65536;
    float s = 0;
#pragma unroll
    for (int i = 0; i < 8; ++i) s += KSp[(size_t)i * 2048 + j];
    Ksum[j] = s;
  }
}

// ---- attention out: msg[l, h*32+v] = (sum_d Q[l,h,d]*KV[h,d,v]) * L/(Q.Ksum+eps)
__global__ __launch_bounds__(256) void attn_kernel(
    const float* __restrict__ Qb, const float* __restrict__ KV,
    const float* __restrict__ Ksum, u16* __restrict__ outb) {
  __shared__ alignas(16) float sKV[8][32][32];
  __shared__ alignas(16) float sKs[256];
  __shared__ alignas(16) float sQ[16][256];
  const int bid = blockIdx.x;
  const int b = bid >> 8, chunk = bid & 255;
  const size_t base = (size_t)b * 4096 + chunk * 16;
  const int t = threadIdx.x;
#pragma unroll
  for (int i = 0; i < 8; ++i)
    ((float4*)sKV)[t + i * 256] = ((const float4*)(KV + (size_t)b * 8192))[t + i * 256];
  sKs[t] = Ksum[b * 256 + t];
#pragma unroll
  for (int i = 0; i < 4; ++i)
    ((float4*)sQ)[t + i * 256] = ((const float4*)(Qb + base * 256))[t + i * 256];
  __syncthreads();
  const int h = t >> 5, dp = t & 31;
  const float* kvh = &sKV[h][0][0];
  for (int l = 0; l < 16; ++l) {
    float zd = 0.f, s = 0.f;
#pragma unroll
    for (int d = 0; d < 32; ++d) {
      float q = sQ[l][h * 32 + d];
      zd += q * sKs[h * 32 + d];
      s += q * kvh[d * 32 + dp];
    }
    float z = 4096.f / (zd + 1e-6f);
    outb[(base + l) * 256 + t] = f2bf(s * z);
  }
}

// ---- LayerNorm over rows of 256; OUTBF=1 -> bf16 dst, else f32 dst ----------
template <int OUTBF>
__global__ __launch_bounds__(256) void ln_kernel(
    const float* __restrict__ src, const float* __restrict__ g,
    const float* __restrict__ bias, void* __restrict__ dst, int dstride, int dcol) {
  int row = blockIdx.x * 4 + (threadIdx.x >> 6);
  int lane = threadIdx.x & 63;
  float4 v = *reinterpret_cast<const float4*>(src + (size_t)row * 256 + lane * 4);
  float s = v.x + v.y + v.z + v.w;
  float sq = v.x * v.x + v.y * v.y + v.z * v.z + v.w * v.w;
#pragma unroll
  for (int off = 32; off; off >>= 1) {
    s += __shfl_xor(s, off);
    sq += __shfl_xor(sq, off);
  }
  float mu = s * (1.f / 256.f);
  float var = sq * (1.f / 256.f) - mu * mu;
  float rstd = rsqrtf(var + 1e-5f);
  float4 gv = *reinterpret_cast<const float4*>(g + lane * 4);
  float4 bv = *reinterpret_cast<const float4*>(bias + lane * 4);
  float y0 = (v.x - mu) * rstd * gv.x + bv.x;
  float y1 = (v.y - mu) * rstd * gv.y + bv.y;
  float y2 = (v.z - mu) * rstd * gv.z + bv.z;
  float y3 = (v.w - mu) * rstd * gv.w + bv.w;
  if (OUTBF) {
    u16* o = (u16*)dst + (size_t)row * dstride + dcol + lane * 4;
    o[0] = f2bf(y0); o[1] = f2bf(y1); o[2] = f2bf(y2); o[3] = f2bf(y3);
  } else {
    float4 o = {y0, y1, y2, y3};
    *reinterpret_cast<float4*>((float*)dst + (size_t)row * dstride + dcol + lane * 4) = o;
  }
}

// ---- out[b,c,l] = x[b,c,l] + msg[b,l,c] ------------------------------------
__global__ __launch_bounds__(256) void transpose_add_kernel(
    const float* __restrict__ x, const float* __restrict__ msg,
    float* __restrict__ out) {
  __shared__ float s[32][33];
  int b = blockIdx.z;
  int lt = blockIdx.x * 32, ct = blockIdx.y * 32;
  int tx = threadIdx.x & 31, ty = threadIdx.x >> 5;
#pragma unroll
  for (int i = 0; i < 4; ++i)
    s[ty + i * 8][tx] = msg[((size_t)b * 4096 + lt + ty + i * 8) * 256 + ct + tx];
  __syncthreads();
#pragma unroll
  for (int i = 0; i < 4; ++i) {
    size_t idx = ((size_t)b * 256 + ct + ty + i * 8) * 4096 + lt + tx;
    out[idx] = x[idx] + s[tx][ty + i * 8];
  }
}

extern "C" void kernel_launch(void* const* d_in, const int* in_sizes, int n_in,
                              void* d_out, int out_size, void* d_ws, size_t ws_size,
                              hipStream_t stream) {
  (void)in_sizes; (void)n_in; (void)out_size; (void)ws_size;
  const float* x = (const float*)d_in[0];
  const float* srcp = (const float*)d_in[1];
  const float* Wq = (const float*)d_in[2];
  const float* Wk = (const float*)d_in[3];
  const float* Wv = (const float*)d_in[4];
  const float* Wm = (const float*)d_in[5];
  const float* W1 = (const float*)d_in[6];
  const float* W2 = (const float*)d_in[7];
  const float* g1 = (const float*)d_in[8];
  const float* b1 = (const float*)d_in[9];
  const float* g2 = (const float*)d_in[10];
  const float* b2 = (const float*)d_in[11];
  float* out = (float*)d_out;
  char* ws = (char*)d_ws;

  u16* wqt = (u16*)(ws + OFF_WQ);
  u16* wkt = (u16*)(ws + OFF_WK);
  u16* wvt = (u16*)(ws + OFF_WV);
  u16* wmt = (u16*)(ws + OFF_WM);
  u16* w1t = (u16*)(ws + OFF_W1);
  u16* w2t = (u16*)(ws + OFF_W2);
  u16* cat = (u16*)(ws + OFF_CAT);
  u16* ssb = (u16*)(ws + OFF_SSB);
  float* Qb = (float*)(ws + OFF_Q);
  float* Kb = (float*)(ws + OFF_K);
  float* Vb = (float*)(ws + OFF_V);
  float* KVb = (float*)(ws + OFF_KV);
  float* KSb = (float*)(ws + OFF_KS);
  u16* attnb = (u16*)(ws + OFF_ATT);
  float* KVp = (float*)(ws + OFF_KVP);
  float* KSp = (float*)(ws + OFF_KSP);
  // region reuse after attention:
  float* wm_out = Vb;             // f32 [M][256]
  u16* hidden = (u16*)(ws + OFF_Q);   // bf16 [M][512]
  float* g2out = Kb;              // f32 [M][256]
  float* ln2out = (float*)(ws + OFF_CAT);  // f32 [M][256]

  dim3 blk(256);
  // weight transpose+cast
  wprep_kernel<<<dim3(8, 8), blk, 0, stream>>>(Wq, wqt, 256, 256);
  wprep_kernel<<<dim3(8, 8), blk, 0, stream>>>(Wk, wkt, 256, 256);
  wprep_kernel<<<dim3(8, 8), blk, 0, stream>>>(Wv, wvt, 256, 256);
  wprep_kernel<<<dim3(8, 8), blk, 0, stream>>>(Wm, wmt, 256, 256);
  wprep_kernel<<<dim3(16, 16), blk, 0, stream>>>(W1, w1t, 512, 512);
  wprep_kernel<<<dim3(16, 8), blk, 0, stream>>>(W2, w2t, 512, 256);
  // input transposes
  transpose_in_kernel<<<dim3(128, 8, 8), blk, 0, stream>>>(x, cat, 512);
  transpose_in_kernel<<<dim3(128, 8, 8), blk, 0, stream>>>(srcp, ssb, 256);
  // q,k,v projections (fused elu+1 / scale epilogues)
  gemm_kernel<1><<<dim3(2, 256), blk, 0, stream>>>(cat, 512, wqt, 256, Qb, 256);
  gemm_kernel<1><<<dim3(2, 256), blk, 0, stream>>>(ssb, 256, wkt, 256, Kb, 256);
  gemm_kernel<2><<<dim3(2, 256), blk, 0, stream>>>(ssb, 256, wvt, 256, Vb, 256);
  // KV / Ksum
  kv_partial_kernel<<<dim3(64, 8), blk, 0, stream>>>(Kb, Vb, KVp, KSp);
  kv_reduce_kernel<<<dim3(264), blk, 0, stream>>>(KVp, KSp, KVb, KSb);
  // attention output (bf16)
  attn_kernel<<<dim3(2048), blk, 0, stream>>>(Qb, KVb, KSb, attnb);
  // msg @ Wm
  gemm_kernel<0><<<dim3(2, 256), blk, 0, stream>>>(attnb, 256, wmt, 256, wm_out, 256);
  // LN1 -> cat[:,256:512] bf16
  ln_kernel<1><<<dim3(8192), blk, 0, stream>>>(wm_out, g1, b1, (void*)cat, 512, 256);
  // MLP
  gemm_kernel<3><<<dim3(4, 256), blk, 0, stream>>>(cat, 512, w1t, 512, hidden, 512);
  gemm_kernel<0><<<dim3(2, 256), blk, 0, stream>>>(hidden, 512, w2t, 512, g2out, 256);
  // LN2 -> f32
  ln_kernel<0><<<dim3(8192), blk, 0, stream>>>(g2out, g2, b2, (void*)ln2out, 256, 0);
  // residual + transpose back to [B,C,L]
  transpose_add_kernel<<<dim3(128, 8, 8), blk, 0, stream>>>(x, ln2out, out);
}

// Round 2
// 201.048 us; speedup vs baseline: 1.0875x; 1.0875x over previous
//
#include <hip/hip_runtime.h>

typedef unsigned short u16;
typedef __bf16 bf16x8 __attribute__((ext_vector_type(8)));
typedef float f32x4 __attribute__((ext_vector_type(4)));

__device__ __forceinline__ u16 f2bf(float f) {
  unsigned int u = __float_as_uint(f);
  u += 0x7fffu + ((u >> 16) & 1u);
  return (u16)(u >> 16);
}

#define GLDS16(gp, lp)                                                   \
  __builtin_amdgcn_global_load_lds(                                      \
      (const __attribute__((address_space(1))) unsigned int*)(gp),       \
      (__attribute__((address_space(3))) unsigned int*)(lp), 16, 0, 0)

// ---- constants -------------------------------------------------------------
// B=8, C=256, H=W=64 -> L=4096, M = B*L = 32768, NHEAD=8, dim=32
// ws layout (bytes)
#define OFF_WQ     0u
#define OFF_WK     131072u     /* wkvt rows 0:256   */
#define OFF_WV     262144u     /* wkvt rows 256:512 */
#define OFF_WM     393216u
#define OFF_W1     524288u
#define OFF_W2     1048576u
#define OFF_CAT    1310720u    /* u16 [M][512] cols 0:256 xs_bf16, 256:512 ln1 */
#define OFF_SSB    34865152u   /* u16 [M][256] ss_bf16 ; later: g2out f32 [M][256] (spans SSB+Q) */
#define OFF_Q      51642368u   /* u16 [M][256] Q=elu(q)+1 bf16 */
#define OFF_KVPROJ 68419584u   /* u16 [M][512] K|vals bf16 ; later: hidden bf16 [M][512] */
#define OFF_WMOUT  101974016u  /* f32 [M][256] wm gemm out */
#define OFF_ATT    135528448u  /* u16 [M][256] attn out bf16 */
#define OFF_KV     152305664u  /* f32 [64][32][32] */
#define OFF_KS     152567808u  /* f32 [64][32] */
#define OFF_KVP    152576000u  /* f32 [8][64][32][32] partials */
#define OFF_KSP    154673152u  /* f32 [8][64][32] partials */

// ---- transposes fp32 [C,L] -> bf16 [L,C] for both x and source --------------
__global__ __launch_bounds__(256) void transpose_in_kernel(
    const float* __restrict__ x, const float* __restrict__ srcp,
    u16* __restrict__ cat, u16* __restrict__ ssb) {
  __shared__ float s[32][33];
  int z = blockIdx.z;
  const float* src = z < 8 ? x : srcp;
  u16* dst = z < 8 ? cat : ssb;
  int dstride = z < 8 ? 512 : 256;
  int b = z & 7;
  int lt = blockIdx.x * 32, ct = blockIdx.y * 32;
  int tx = threadIdx.x & 31, ty = threadIdx.x >> 5;
#pragma unroll
  for (int i = 0; i < 4; ++i)
    s[ty + i * 8][tx] = src[((size_t)b * 256 + ct + ty + i * 8) * 4096 + lt + tx];
  __syncthreads();
#pragma unroll
  for (int i = 0; i < 4; ++i)
    dst[((size_t)b * 4096 + lt + ty + i * 8) * dstride + ct + tx] = f2bf(s[tx][ty + i * 8]);
}

// ---- all weight preps in one dispatch: fp32 [K,N] -> bf16 [N,K] ------------
__global__ __launch_bounds__(256) void wprep_all_kernel(
    const float* __restrict__ Wq, const float* __restrict__ Wk,
    const float* __restrict__ Wv, const float* __restrict__ Wm,
    const float* __restrict__ W1, const float* __restrict__ W2,
    u16* __restrict__ dq, u16* __restrict__ dk, u16* __restrict__ dv,
    u16* __restrict__ dm, u16* __restrict__ d1, u16* __restrict__ d2) {
  __shared__ float s[32][33];
  int bid = blockIdx.x;
  const float* src; u16* dst; int Kd, Nd, t;
  if (bid < 64)       { src = Wq; dst = dq; Kd = 256; Nd = 256; t = bid; }
  else if (bid < 128) { src = Wk; dst = dk; Kd = 256; Nd = 256; t = bid - 64; }
  else if (bid < 192) { src = Wv; dst = dv; Kd = 256; Nd = 256; t = bid - 128; }
  else if (bid < 256) { src = Wm; dst = dm; Kd = 256; Nd = 256; t = bid - 192; }
  else if (bid < 512) { src = W1; dst = d1; Kd = 512; Nd = 512; t = bid - 256; }
  else                { src = W2; dst = d2; Kd = 512; Nd = 256; t = bid - 512; }
  int ntn = Nd >> 5;
  int kt = (t / ntn) * 32, nt = (t % ntn) * 32;
  int tx = threadIdx.x & 31, ty = threadIdx.x >> 5;
#pragma unroll
  for (int i = 0; i < 4; ++i)
    s[ty + i * 8][tx] = src[(size_t)(kt + ty + i * 8) * Nd + nt + tx];
  __syncthreads();
#pragma unroll
  for (int i = 0; i < 4; ++i)
    dst[(size_t)(nt + ty + i * 8) * Kd + kt + tx] = f2bf(s[tx][ty + i * 8]);
}

// ---- bf16 MFMA GEMM: out[M,N] = A[M,K] @ Wt[N,K]^T -------------------------
// 128x128 tile, 4 waves (2x2), 64x64/wave via 4x4 frags of 16x16x32.
// global_load_lds(16B) staging, linear LDS (m97 structure).
// EPI: 0 plain f32 | 1 elu+1 bf16 | 3 relu bf16 | 4 fused kv (col<256 elu+1, else /4096) bf16
template <int EPI>
__global__ __launch_bounds__(256) void gemm_kernel(
    const u16* __restrict__ A, int lda, const u16* __restrict__ Wt, int K,
    void* __restrict__ outp, int ldo) {
  __shared__ alignas(16) u16 sA[128 * 64];
  __shared__ alignas(16) u16 sB[128 * 64];
  const int tid = threadIdx.x;
  const int m0 = blockIdx.y * 128, n0 = blockIdx.x * 128;
  const int w = tid >> 6, lane = tid & 63;
  const int wm = (w >> 1) * 64, wn = (w & 1) * 64;
  const int lr = lane & 15, lk = lane >> 4;
  f32x4 acc[4][4] = {};
  const int srow = tid >> 3, sch = (tid & 7) << 3;
  const u16* ga = A + (size_t)(m0 + srow) * lda + sch;
  const u16* gb = Wt + (size_t)(n0 + srow) * K + sch;

  const int nkt = K >> 6;
  for (int kt = 0; kt < nkt; ++kt) {
    __syncthreads();
#pragma unroll
    for (int i = 0; i < 4; ++i) {
      GLDS16(ga + (size_t)i * 32 * lda + kt * 64, sA + (tid + i * 256) * 8);
      GLDS16(gb + (size_t)i * 32 * K + kt * 64, sB + (tid + i * 256) * 8);
    }
    __syncthreads();
    bf16x8 af[4][2], bfr[4][2];
#pragma unroll
    for (int f = 0; f < 4; ++f) {
#pragma unroll
      for (int ks = 0; ks < 2; ++ks) {
        af[f][ks] = *reinterpret_cast<const bf16x8*>(
            &sA[(wm + f * 16 + lr) * 64 + ks * 32 + lk * 8]);
        bfr[f][ks] = *reinterpret_cast<const bf16x8*>(
            &sB[(wn + f * 16 + lr) * 64 + ks * 32 + lk * 8]);
      }
    }
#pragma unroll
    for (int ks = 0; ks < 2; ++ks)
#pragma unroll
      for (int fm = 0; fm < 4; ++fm)
#pragma unroll
        for (int fn = 0; fn < 4; ++fn)
          acc[fm][fn] = __builtin_amdgcn_mfma_f32_16x16x32_bf16(
              af[fm][ks], bfr[fn][ks], acc[fm][fn], 0, 0, 0);
  }

  const int r0 = (lane >> 4) * 4, c0 = lane & 15;
#pragma unroll
  for (int fm = 0; fm < 4; ++fm) {
#pragma unroll
    for (int fn = 0; fn < 4; ++fn) {
      int gr = m0 + wm + fm * 16 + r0;
      int gc = n0 + wn + fn * 16 + c0;
#pragma unroll
      for (int r = 0; r < 4; ++r) {
        float v = acc[fm][fn][r];
        if (EPI == 1) {
          v = v > 0.f ? v + 1.f : __expf(v);
          ((u16*)outp)[(size_t)(gr + r) * ldo + gc] = f2bf(v);
        } else if (EPI == 3) {
          v = v > 0.f ? v : 0.f;
          ((u16*)outp)[(size_t)(gr + r) * ldo + gc] = f2bf(v);
        } else if (EPI == 4) {
          v = (gc < 256) ? (v > 0.f ? v + 1.f : __expf(v)) : v * (1.f / 4096.f);
          ((u16*)outp)[(size_t)(gr + r) * ldo + gc] = f2bf(v);
        } else {
          ((float*)outp)[(size_t)(gr + r) * ldo + gc] = v;
        }
      }
    }
  }
}

// ---- KV partial: KVp[s,bh,d,v] = sum_{l in slice} K[l,d]*vals[l,v] ----------
// reads bf16 KVproj [M][512] (K cols 0:256, vals cols 256:512)
__global__ __launch_bounds__(256) void kv_partial_kernel(
    const u16* __restrict__ KVproj, float* __restrict__ KVp,
    float* __restrict__ KSp) {
  __shared__ alignas(16) float sK[64][32];
  __shared__ alignas(16) float sV[64][32];
  const int bh = blockIdx.x, sl = blockIdx.y;
  const int b = bh >> 3, h = bh & 7;
  const int t = threadIdx.x;
  const int lrow = t >> 2, lcol = (t & 3) * 8;
  const int d = t >> 3, vg = (t & 7) * 4;
  float a0 = 0, a1 = 0, a2 = 0, a3 = 0, ks = 0;
  for (int lt = 0; lt < 512; lt += 64) {
    __syncthreads();
    size_t roff = ((size_t)b * 4096 + sl * 512 + lt + lrow) * 512 + h * 32 + lcol;
    uint4 kq = *reinterpret_cast<const uint4*>(KVproj + roff);
    uint4 vq = *reinterpret_cast<const uint4*>(KVproj + roff + 256);
    float* dk = &sK[lrow][lcol];
    float* dv = &sV[lrow][lcol];
#pragma unroll
    for (int j = 0; j < 4; ++j) {
      unsigned uk = ((const unsigned*)&kq)[j];
      unsigned uv = ((const unsigned*)&vq)[j];
      dk[2 * j] = __uint_as_float(uk << 16);
      dk[2 * j + 1] = __uint_as_float(uk & 0xffff0000u);
      dv[2 * j] = __uint_as_float(uv << 16);
      dv[2 * j + 1] = __uint_as_float(uv & 0xffff0000u);
    }
    __syncthreads();
#pragma unroll 8
    for (int i = 0; i < 64; ++i) {
      float kd = sK[i][d];
      a0 += kd * sV[i][vg + 0];
      a1 += kd * sV[i][vg + 1];
      a2 += kd * sV[i][vg + 2];
      a3 += kd * sV[i][vg + 3];
      ks += kd;
    }
  }
  float* o = KVp + (size_t)sl * 65536 + bh * 1024 + d * 32 + vg;
  o[0] = a0; o[1] = a1; o[2] = a2; o[3] = a3;
  if ((t & 7) == 0) KSp[(size_t)sl * 2048 + bh * 32 + d] = ks;
}

__global__ __launch_bounds__(256) void kv_reduce_kernel(
    const float* __restrict__ KVp, const float* __restrict__ KSp,
    float* __restrict__ KV, float* __restrict__ Ksum) {
  int gid = blockIdx.x * 256 + threadIdx.x;
  if (gid < 65536) {
    float s = 0;
#pragma unroll
    for (int i = 0; i < 8; ++i) s += KVp[(size_t)i * 65536 + gid];
    KV[gid] = s;
  } else if (gid - 65536 < 2048) {
    int j = gid - 65536;
    float s = 0;
#pragma unroll
    for (int i = 0; i < 8; ++i) s += KSp[(size_t)i * 2048 + j];
    Ksum[j] = s;
  }
}

// ---- attention out: msg[l, h*32+v] = (sum_d Q[l,h,d]*KV[h,d,v]) * L/(Q.Ksum+eps)
// Q is bf16 [M][256]; out bf16.
__global__ __launch_bounds__(256) void attn_kernel(
    const u16* __restrict__ Qb, const float* __restrict__ KV,
    const float* __restrict__ Ksum, u16* __restrict__ outb) {
  __shared__ alignas(16) float sKV[8][32][32];
  __shared__ alignas(16) float sKs[256];
  __shared__ alignas(16) float sQ[16][256];
  const int bid = blockIdx.x;
  const int b = bid >> 8, chunk = bid & 255;
  const size_t base = (size_t)b * 4096 + chunk * 16;
  const int t = threadIdx.x;
#pragma unroll
  for (int i = 0; i < 8; ++i)
    ((float4*)sKV)[t + i * 256] = ((const float4*)(KV + (size_t)b * 8192))[t + i * 256];
  sKs[t] = Ksum[b * 256 + t];
  {
    const u16* qsrc = Qb + base * 256;
    uint4 qa = ((const uint4*)qsrc)[t];
    uint4 qc = ((const uint4*)qsrc)[t + 256];
    float* sQf = (float*)sQ;
#pragma unroll
    for (int j = 0; j < 4; ++j) {
      unsigned u = ((const unsigned*)&qa)[j];
      sQf[t * 8 + 2 * j] = __uint_as_float(u << 16);
      sQf[t * 8 + 2 * j + 1] = __uint_as_float(u & 0xffff0000u);
      unsigned u2 = ((const unsigned*)&qc)[j];
      sQf[2048 + t * 8 + 2 * j] = __uint_as_float(u2 << 16);
      sQf[2048 + t * 8 + 2 * j + 1] = __uint_as_float(u2 & 0xffff0000u);
    }
  }
  __syncthreads();
  const int h = t >> 5, dp = t & 31;
  const float* kvh = &sKV[h][0][0];
  for (int l = 0; l < 16; ++l) {
    float zd = 0.f, s = 0.f;
#pragma unroll
    for (int d = 0; d < 32; ++d) {
      float q = sQ[l][h * 32 + d];
      zd += q * sKs[h * 32 + d];
      s += q * kvh[d * 32 + dp];
    }
    float z = 4096.f / (zd + 1e-6f);
    outb[(base + l) * 256 + t] = f2bf(s * z);
  }
}

// ---- LayerNorm rows of 256 -> bf16 dst (used for LN1 into cat cols 256:512)
__global__ __launch_bounds__(256) void ln_kernel(
    const float* __restrict__ src, const float* __restrict__ g,
    const float* __restrict__ bias, u16* __restrict__ dst, int dstride, int dcol) {
  int row = blockIdx.x * 4 + (threadIdx.x >> 6);
  int lane = threadIdx.x & 63;
  float4 v = *reinterpret_cast<const float4*>(src + (size_t)row * 256 + lane * 4);
  float s = v.x + v.y + v.z + v.w;
  float sq = v.x * v.x + v.y * v.y + v.z * v.z + v.w * v.w;
#pragma unroll
  for (int off = 32; off; off >>= 1) {
    s += __shfl_xor(s, off);
    sq += __shfl_xor(sq, off);
  }
  float mu = s * (1.f / 256.f);
  float var = sq * (1.f / 256.f) - mu * mu;
  float rstd = rsqrtf(var + 1e-5f);
  float4 gv = *reinterpret_cast<const float4*>(g + lane * 4);
  float4 bv = *reinterpret_cast<const float4*>(bias + lane * 4);
  u16* o = dst + (size_t)row * dstride + dcol + lane * 4;
  o[0] = f2bf((v.x - mu) * rstd * gv.x + bv.x);
  o[1] = f2bf((v.y - mu) * rstd * gv.y + bv.y);
  o[2] = f2bf((v.z - mu) * rstd * gv.z + bv.z);
  o[3] = f2bf((v.w - mu) * rstd * gv.w + bv.w);
}

// ---- fused LN2 + transpose + residual: out[b,c,l] = x[b,c,l] + LN(src)[l,c] -
__global__ __launch_bounds__(256) void ln2_ta_kernel(
    const float* __restrict__ src, const float* __restrict__ g,
    const float* __restrict__ bias, const float* __restrict__ x,
    float* __restrict__ out) {
  __shared__ float sbuf[256 * 33];
  const int b = blockIdx.y, l0 = blockIdx.x * 32;
  const int t = threadIdx.x;
  // phase 1: stage 32 rows x 256 cols f32
  const float4* srcv = (const float4*)(src + ((size_t)b * 4096 + l0) * 256);
#pragma unroll
  for (int i = 0; i < 8; ++i)
    ((float4*)sbuf)[t + i * 256] = srcv[t + i * 256];
  __syncthreads();
  // phase 2: LN per row; wave wv handles rows wv*8..wv*8+7
  const int lane = t & 63, wv = t >> 6;
  float4 gv = ((const float4*)g)[lane];
  float4 bv = ((const float4*)bias)[lane];
  float y[8][4];
#pragma unroll
  for (int it = 0; it < 8; ++it) {
    int r = wv * 8 + it;
    float4 v = ((const float4*)&sbuf[r * 256])[lane];
    float s = v.x + v.y + v.z + v.w;
    float sq = v.x * v.x + v.y * v.y + v.z * v.z + v.w * v.w;
#pragma unroll
    for (int off = 32; off; off >>= 1) {
      s += __shfl_xor(s, off);
      sq += __shfl_xor(sq, off);
    }
    float mu = s * (1.f / 256.f);
    float var = sq * (1.f / 256.f) - mu * mu;
    float rstd = rsqrtf(var + 1e-5f);
    y[it][0] = (v.x - mu) * rstd * gv.x + bv.x;
    y[it][1] = (v.y - mu) * rstd * gv.y + bv.y;
    y[it][2] = (v.z - mu) * rstd * gv.z + bv.z;
    y[it][3] = (v.w - mu) * rstd * gv.w + bv.w;
  }
  __syncthreads();
  // phase 3: write transposed into sbuf reinterpreted as [256][33]
#pragma unroll
  for (int it = 0; it < 8; ++it) {
    int r = wv * 8 + it;
#pragma unroll
    for (int j = 0; j < 4; ++j) sbuf[(lane * 4 + j) * 33 + r] = y[it][j];
  }
  __syncthreads();
  // phase 4: out[b,c,l0+lx] = x + y^T
  const int lx = t & 31, c0 = t >> 5;
#pragma unroll
  for (int j = 0; j < 32; ++j) {
    int c = j * 8 + c0;
    size_t idx = ((size_t)b * 256 + c) * 4096 + l0 + lx;
    out[idx] = x[idx] + sbuf[c * 33 + lx];
  }
}

extern "C" void kernel_launch(void* const* d_in, const int* in_sizes, int n_in,
                              void* d_out, int out_size, void* d_ws, size_t ws_size,
                              hipStream_t stream) {
  (void)in_sizes; (void)n_in; (void)out_size; (void)ws_size;
  const float* x = (const float*)d_in[0];
  const float* srcp = (const float*)d_in[1];
  const float* Wq = (const float*)d_in[2];
  const float* Wk = (const float*)d_in[3];
  const float* Wv = (const float*)d_in[4];
  const float* Wm = (const float*)d_in[5];
  const float* W1 = (const float*)d_in[6];
  const float* W2 = (const float*)d_in[7];
  const float* g1 = (const float*)d_in[8];
  const float* b1 = (const float*)d_in[9];
  const float* g2 = (const float*)d_in[10];
  const float* b2 = (const float*)d_in[11];
  float* out = (float*)d_out;
  char* ws = (char*)d_ws;

  u16* wqt = (u16*)(ws + OFF_WQ);
  u16* wkvt = (u16*)(ws + OFF_WK);      // [512][256] = Wk^T | Wv^T
  u16* wkt = (u16*)(ws + OFF_WK);
  u16* wvt = (u16*)(ws + OFF_WV);
  u16* wmt = (u16*)(ws + OFF_WM);
  u16* w1t = (u16*)(ws + OFF_W1);
  u16* w2t = (u16*)(ws + OFF_W2);
  u16* cat = (u16*)(ws + OFF_CAT);
  u16* ssb = (u16*)(ws + OFF_SSB);
  u16* Qb = (u16*)(ws + OFF_Q);
  u16* kvproj = (u16*)(ws + OFF_KVPROJ);
  float* wm_out = (float*)(ws + OFF_WMOUT);
  u16* attnb = (u16*)(ws + OFF_ATT);
  float* KVb = (float*)(ws + OFF_KV);
  float* KSb = (float*)(ws + OFF_KS);
  float* KVp = (float*)(ws + OFF_KVP);
  float* KSp = (float*)(ws + OFF_KSP);
  // region reuse:
  u16* hidden = kvproj;                 // bf16 [M][512], after kv_partial done
  float* g2out = (float*)(ws + OFF_SSB); // f32 [M][256], after ssb+Qb dead

  dim3 blk(256);
  wprep_all_kernel<<<dim3(640), blk, 0, stream>>>(Wq, Wk, Wv, Wm, W1, W2,
                                                  wqt, wkt, wvt, wmt, w1t, w2t);
  transpose_in_kernel<<<dim3(128, 8, 16), blk, 0, stream>>>(x, srcp, cat, ssb);
  // q projection (elu+1, bf16 out)
  gemm_kernel<1><<<dim3(2, 256), blk, 0, stream>>>(cat, 512, wqt, 256, Qb, 256);
  // fused k|v projection (elu+1 | /L, bf16 out [M][512])
  gemm_kernel<4><<<dim3(4, 256), blk, 0, stream>>>(ssb, 256, wkvt, 256, kvproj, 512);
  // KV / Ksum
  kv_partial_kernel<<<dim3(64, 8), blk, 0, stream>>>(kvproj, KVp, KSp);
  kv_reduce_kernel<<<dim3(264), blk, 0, stream>>>(KVp, KSp, KVb, KSb);
  // attention output (bf16)
  attn_kernel<<<dim3(2048), blk, 0, stream>>>(Qb, KVb, KSb, attnb);
  // msg @ Wm -> f32
  gemm_kernel<0><<<dim3(2, 256), blk, 0, stream>>>(attnb, 256, wmt, 256, wm_out, 256);
  // LN1 -> cat[:,256:512] bf16
  ln_kernel<<<dim3(8192), blk, 0, stream>>>(wm_out, g1, b1, cat, 512, 256);
  // MLP
  gemm_kernel<3><<<dim3(4, 256), blk, 0, stream>>>(cat, 512, w1t, 512, hidden, 512);
  gemm_kernel<0><<<dim3(2, 256), blk, 0, stream>>>(hidden, 512, w2t, 512, g2out, 256);
  // LN2 + transpose + residual
  ln2_ta_kernel<<<dim3(128, 8), blk, 0, stream>>>(g2out, g2, b2, x, out);
}

// Round 3
// 194.127 us; speedup vs baseline: 1.1262x; 1.0357x over previous
//
#include <hip/hip_runtime.h>

typedef unsigned short u16;
typedef __bf16 bf16x8 __attribute__((ext_vector_type(8)));
typedef float f32x4 __attribute__((ext_vector_type(4)));

__device__ __forceinline__ u16 f2bf(float f) {
  unsigned int u = __float_as_uint(f);
  u += 0x7fffu + ((u >> 16) & 1u);
  return (u16)(u >> 16);
}

#define GLDS16(gp, lp)                                                   \
  __builtin_amdgcn_global_load_lds(                                      \
      (const __attribute__((address_space(1))) unsigned int*)(gp),       \
      (__attribute__((address_space(3))) unsigned int*)(lp), 16, 0, 0)

// B=8, C=256, L=4096, M=32768, NHEAD=8, dim=32
// ws layout (bytes)
#define OFF_WQ     0u
#define OFF_WK     131072u     /* wkvt rows 0:256 */
#define OFF_WV     262144u
#define OFF_WM     393216u
#define OFF_W1     524288u
#define OFF_W2     1048576u
#define OFF_CAT    1310720u    /* u16 [M][512]: 0:256 xs, 256:512 ln1 */
#define OFF_SSB    34865152u   /* u16 [M][256] ss_bf16 */
#define OFF_Q      51642368u   /* u16 [M][256] Q bf16 */
#define OFF_KVPROJ 68419584u   /* u16 [M][512] K|vals bf16 ; later hidden */
#define OFF_KV     152305664u  /* f32 [64][32][32] */
#define OFF_KS     152567808u  /* f32 [64][32] */
#define OFF_KVP    152576000u  /* f32 [8][64][32][32] partials */
#define OFF_KSP    154673152u  /* f32 [8][64][32] partials */

// ---- transposes fp32 [C,L] -> bf16 [L,C] ------------------------------------
__global__ __launch_bounds__(256) void transpose_in_kernel(
    const float* __restrict__ x, const float* __restrict__ srcp,
    u16* __restrict__ cat, u16* __restrict__ ssb) {
  __shared__ float s[32][33];
  int z = blockIdx.z;
  const float* src = z < 8 ? x : srcp;
  u16* dst = z < 8 ? cat : ssb;
  int dstride = z < 8 ? 512 : 256;
  int b = z & 7;
  int lt = blockIdx.x * 32, ct = blockIdx.y * 32;
  int tx = threadIdx.x & 31, ty = threadIdx.x >> 5;
#pragma unroll
  for (int i = 0; i < 4; ++i)
    s[ty + i * 8][tx] = src[((size_t)b * 256 + ct + ty + i * 8) * 4096 + lt + tx];
  __syncthreads();
#pragma unroll
  for (int i = 0; i < 4; ++i)
    dst[((size_t)b * 4096 + lt + ty + i * 8) * dstride + ct + tx] = f2bf(s[tx][ty + i * 8]);
}

// ---- weight prep: fp32 [K,N] -> bf16 [N,K], all weights one dispatch --------
__global__ __launch_bounds__(256) void wprep_all_kernel(
    const float* __restrict__ Wq, const float* __restrict__ Wk,
    const float* __restrict__ Wv, const float* __restrict__ Wm,
    const float* __restrict__ W1, const float* __restrict__ W2,
    u16* __restrict__ dq, u16* __restrict__ dk, u16* __restrict__ dv,
    u16* __restrict__ dm, u16* __restrict__ d1, u16* __restrict__ d2) {
  __shared__ float s[32][33];
  int bid = blockIdx.x;
  const float* src; u16* dst; int Kd, Nd, t;
  if (bid < 64)       { src = Wq; dst = dq; Kd = 256; Nd = 256; t = bid; }
  else if (bid < 128) { src = Wk; dst = dk; Kd = 256; Nd = 256; t = bid - 64; }
  else if (bid < 192) { src = Wv; dst = dv; Kd = 256; Nd = 256; t = bid - 128; }
  else if (bid < 256) { src = Wm; dst = dm; Kd = 256; Nd = 256; t = bid - 192; }
  else if (bid < 512) { src = W1; dst = d1; Kd = 512; Nd = 512; t = bid - 256; }
  else                { src = W2; dst = d2; Kd = 512; Nd = 256; t = bid - 512; }
  int ntn = Nd >> 5;
  int kt = (t / ntn) * 32, nt = (t % ntn) * 32;
  int tx = threadIdx.x & 31, ty = threadIdx.x >> 5;
#pragma unroll
  for (int i = 0; i < 4; ++i)
    s[ty + i * 8][tx] = src[(size_t)(kt + ty + i * 8) * Nd + nt + tx];
  __syncthreads();
#pragma unroll
  for (int i = 0; i < 4; ++i)
    dst[(size_t)(nt + ty + i * 8) * Kd + kt + tx] = f2bf(s[tx][ty + i * 8]);
}

// ---- bf16 MFMA GEMM, 128x128 tile, 4 waves, gload_lds staging ---------------
// EPI: 1 elu+1 bf16 | 3 relu bf16 | 4 fused kv (col<256 elu+1, else /4096) bf16
template <int EPI>
__global__ __launch_bounds__(256) void gemm_kernel(
    const u16* __restrict__ A, int lda, const u16* __restrict__ Wt, int K,
    u16* __restrict__ outp, int ldo) {
  __shared__ alignas(16) u16 sA[128 * 64];
  __shared__ alignas(16) u16 sB[128 * 64];
  const int tid = threadIdx.x;
  const int m0 = blockIdx.y * 128, n0 = blockIdx.x * 128;
  const int w = tid >> 6, lane = tid & 63;
  const int wm = (w >> 1) * 64, wn = (w & 1) * 64;
  const int lr = lane & 15, lk = lane >> 4;
  f32x4 acc[4][4] = {};
  const int srow = tid >> 3, sch = (tid & 7) << 3;
  const u16* ga = A + (size_t)(m0 + srow) * lda + sch;
  const u16* gb = Wt + (size_t)(n0 + srow) * K + sch;

  const int nkt = K >> 6;
  for (int kt = 0; kt < nkt; ++kt) {
    __syncthreads();
#pragma unroll
    for (int i = 0; i < 4; ++i) {
      GLDS16(ga + (size_t)i * 32 * lda + kt * 64, sA + (tid + i * 256) * 8);
      GLDS16(gb + (size_t)i * 32 * K + kt * 64, sB + (tid + i * 256) * 8);
    }
    __syncthreads();
    bf16x8 af[4][2], bfr[4][2];
#pragma unroll
    for (int f = 0; f < 4; ++f) {
#pragma unroll
      for (int ks = 0; ks < 2; ++ks) {
        af[f][ks] = *reinterpret_cast<const bf16x8*>(
            &sA[(wm + f * 16 + lr) * 64 + ks * 32 + lk * 8]);
        bfr[f][ks] = *reinterpret_cast<const bf16x8*>(
            &sB[(wn + f * 16 + lr) * 64 + ks * 32 + lk * 8]);
      }
    }
#pragma unroll
    for (int ks = 0; ks < 2; ++ks)
#pragma unroll
      for (int fm = 0; fm < 4; ++fm)
#pragma unroll
        for (int fn = 0; fn < 4; ++fn)
          acc[fm][fn] = __builtin_amdgcn_mfma_f32_16x16x32_bf16(
              af[fm][ks], bfr[fn][ks], acc[fm][fn], 0, 0, 0);
  }

  const int r0 = (lane >> 4) * 4, c0 = lane & 15;
#pragma unroll
  for (int fm = 0; fm < 4; ++fm) {
#pragma unroll
    for (int fn = 0; fn < 4; ++fn) {
      int gr = m0 + wm + fm * 16 + r0;
      int gc = n0 + wn + fn * 16 + c0;
#pragma unroll
      for (int r = 0; r < 4; ++r) {
        float v = acc[fm][fn][r];
        if (EPI == 1) v = v > 0.f ? v + 1.f : __expf(v);
        if (EPI == 3) v = v > 0.f ? v : 0.f;
        if (EPI == 4) v = (gc < 256) ? (v > 0.f ? v + 1.f : __expf(v)) : v * (1.f / 4096.f);
        outp[(size_t)(gr + r) * ldo + gc] = f2bf(v);
      }
    }
  }
}

// ---- KV partial over L-slices (reads bf16 kvproj [M][512]) ------------------
__global__ __launch_bounds__(256) void kv_partial_kernel(
    const u16* __restrict__ KVproj, float* __restrict__ KVp,
    float* __restrict__ KSp) {
  __shared__ alignas(16) float sK[64][32];
  __shared__ alignas(16) float sV[64][32];
  const int bh = blockIdx.x, sl = blockIdx.y;
  const int b = bh >> 3, h = bh & 7;
  const int t = threadIdx.x;
  const int lrow = t >> 2, lcol = (t & 3) * 8;
  const int d = t >> 3, vg = (t & 7) * 4;
  float a0 = 0, a1 = 0, a2 = 0, a3 = 0, ks = 0;
  for (int lt = 0; lt < 512; lt += 64) {
    __syncthreads();
    size_t roff = ((size_t)b * 4096 + sl * 512 + lt + lrow) * 512 + h * 32 + lcol;
    uint4 kq = *reinterpret_cast<const uint4*>(KVproj + roff);
    uint4 vq = *reinterpret_cast<const uint4*>(KVproj + roff + 256);
    float* dk = &sK[lrow][lcol];
    float* dv = &sV[lrow][lcol];
#pragma unroll
    for (int j = 0; j < 4; ++j) {
      unsigned uk = ((const unsigned*)&kq)[j];
      unsigned uv = ((const unsigned*)&vq)[j];
      dk[2 * j] = __uint_as_float(uk << 16);
      dk[2 * j + 1] = __uint_as_float(uk & 0xffff0000u);
      dv[2 * j] = __uint_as_float(uv << 16);
      dv[2 * j + 1] = __uint_as_float(uv & 0xffff0000u);
    }
    __syncthreads();
#pragma unroll 8
    for (int i = 0; i < 64; ++i) {
      float kd = sK[i][d];
      a0 += kd * sV[i][vg + 0];
      a1 += kd * sV[i][vg + 1];
      a2 += kd * sV[i][vg + 2];
      a3 += kd * sV[i][vg + 3];
      ks += kd;
    }
  }
  float* o = KVp + (size_t)sl * 65536 + bh * 1024 + d * 32 + vg;
  o[0] = a0; o[1] = a1; o[2] = a2; o[3] = a3;
  if ((t & 7) == 0) KSp[(size_t)sl * 2048 + bh * 32 + d] = ks;
}

__global__ __launch_bounds__(256) void kv_reduce_kernel(
    const float* __restrict__ KVp, const float* __restrict__ KSp,
    float* __restrict__ KV, float* __restrict__ Ksum) {
  int gid = blockIdx.x * 256 + threadIdx.x;
  if (gid < 65536) {
    float s = 0;
#pragma unroll
    for (int i = 0; i < 8; ++i) s += KVp[(size_t)i * 65536 + gid];
    KV[gid] = s;
  } else if (gid - 65536 < 2048) {
    int j = gid - 65536;
    float s = 0;
#pragma unroll
    for (int i = 0; i < 8; ++i) s += KSp[(size_t)i * 2048 + j];
    Ksum[j] = s;
  }
}

// ---- FUSED: attention + msg@Wm + LN1 -> cat[:,256:512] ----------------------
// BM=64 rows/block, grid 512, 512 threads (8 waves; wave w owns cols w*32..+32)
__global__ __launch_bounds__(512) void attn_wm_ln1_kernel(
    const u16* __restrict__ Qb, const float* __restrict__ KVb,
    const float* __restrict__ KSb, const u16* __restrict__ WmT,
    const float* __restrict__ g1, const float* __restrict__ b1,
    u16* __restrict__ cat) {
  __shared__ float sQ[16 * 256];          // 16KB one 16-row Q chunk (f32)
  __shared__ float sKs[256];              // 1KB
  __shared__ float sZ[64 * 8];            // 2KB  L*Z per (row, head)
  __shared__ alignas(16) u16 sAttn[64 * 264];  // 33KB, padded stride 264
  __shared__ float sScr[64 * 16];         // 4KB LN cross-wave scratch
  __shared__ float sG[512];               // g1 | b1
  const int t = threadIdx.x;
  const int m0 = blockIdx.x * 64;
  const int b = m0 >> 12;
  if (t < 256) { sKs[t] = KSb[b * 256 + t]; sG[t] = g1[t]; sG[256 + t] = b1[t]; }
  // preload this thread's KV column (32 f32)
  const int c = t & 255, h = c >> 5, v = c & 31;
  float kvcol[32];
  {
    const float* kvp = KVb + ((size_t)b * 8 + h) * 1024 + v;
#pragma unroll
    for (int d = 0; d < 32; ++d) kvcol[d] = kvp[d * 32];
  }
  const int rh = t >> 8;  // row-half within chunk
  // ---- attention phase: 4 chunks of 16 rows ----
  for (int ch = 0; ch < 4; ++ch) {
    __syncthreads();  // protect sQ reuse
    {   // stage Q chunk as f32
      uint4 q = *((const uint4*)(Qb + ((size_t)m0 + ch * 16) * 256) + t);
      float* dst = sQ + t * 8;
#pragma unroll
      for (int j = 0; j < 4; ++j) {
        unsigned u = ((const unsigned*)&q)[j];
        dst[2 * j] = __uint_as_float(u << 16);
        dst[2 * j + 1] = __uint_as_float(u & 0xffff0000u);
      }
    }
    __syncthreads();
    if (t < 128) {  // z-pass: one (row, head) per thread
      int l = t >> 3, hh = t & 7;
      const float* q = sQ + l * 256 + hh * 32;
      const float* ks = sKs + hh * 32;
      float zd = 0.f;
#pragma unroll
      for (int d = 0; d < 32; ++d) zd += q[d] * ks[d];
      sZ[(ch * 16 + l) * 8 + hh] = 4096.f / (zd + 1e-6f);
    }
    __syncthreads();
#pragma unroll
    for (int i = 0; i < 8; ++i) {  // s-dot: thread (c, rh) does 8 rows
      int l = rh * 8 + i;
      const float* q = sQ + l * 256 + h * 32;
      float s0 = 0.f, s1 = 0.f, s2 = 0.f, s3 = 0.f;
#pragma unroll
      for (int d = 0; d < 32; d += 4) {
        s0 += q[d] * kvcol[d];
        s1 += q[d + 1] * kvcol[d + 1];
        s2 += q[d + 2] * kvcol[d + 2];
        s3 += q[d + 3] * kvcol[d + 3];
      }
      int gl = ch * 16 + l;
      sAttn[gl * 264 + c] = f2bf((s0 + s1 + s2 + s3) * sZ[gl * 8 + h]);
    }
  }
  __syncthreads();
  // ---- Wm GEMM: sAttn[64][256] @ WmT^T ; wave w -> cols w*32..w*32+32 ----
  const int w = t >> 6, lane = t & 63;
  const int wn = w * 32;
  const int lr = lane & 15, lk = lane >> 4;
  f32x4 acc[4][2] = {};
  bf16x8 bfr[8][2];
#pragma unroll
  for (int kc = 0; kc < 8; ++kc)
#pragma unroll
    for (int fn = 0; fn < 2; ++fn)
      bfr[kc][fn] = *reinterpret_cast<const bf16x8*>(
          WmT + (size_t)(wn + fn * 16 + lr) * 256 + kc * 32 + lk * 8);
#pragma unroll
  for (int kc = 0; kc < 8; ++kc) {
    bf16x8 af[4];
#pragma unroll
    for (int f = 0; f < 4; ++f)
      af[f] = *reinterpret_cast<const bf16x8*>(
          &sAttn[(f * 16 + lr) * 264 + kc * 32 + lk * 8]);
#pragma unroll
    for (int fm = 0; fm < 4; ++fm)
#pragma unroll
      for (int fn = 0; fn < 2; ++fn)
        acc[fm][fn] = __builtin_amdgcn_mfma_f32_16x16x32_bf16(
            af[fm], bfr[kc][fn], acc[fm][fn], 0, 0, 0);
  }
  // ---- LN1 (cross-wave) ----
  // lane rows: fm*16 + lk*4 + r ; cols: wn + fn*16 + lr
  float ps[4][4], pq[4][4];
#pragma unroll
  for (int fm = 0; fm < 4; ++fm)
#pragma unroll
    for (int r = 0; r < 4; ++r) {
      float a = acc[fm][0][r], bb = acc[fm][1][r];
      float s = a + bb, sq = a * a + bb * bb;
#pragma unroll
      for (int off = 1; off < 16; off <<= 1) {
        s += __shfl_xor(s, off);
        sq += __shfl_xor(sq, off);
      }
      ps[fm][r] = s; pq[fm][r] = sq;
    }
  if (lr == 0) {
#pragma unroll
    for (int fm = 0; fm < 4; ++fm)
#pragma unroll
      for (int r = 0; r < 4; ++r) {
        int row = fm * 16 + lk * 4 + r;
        sScr[row * 16 + w * 2] = ps[fm][r];
        sScr[row * 16 + w * 2 + 1] = pq[fm][r];
      }
  }
  __syncthreads();
  float gv0 = sG[wn + lr], gv1 = sG[wn + 16 + lr];
  float bv0 = sG[256 + wn + lr], bv1 = sG[256 + wn + 16 + lr];
#pragma unroll
  for (int fm = 0; fm < 4; ++fm)
#pragma unroll
    for (int r = 0; r < 4; ++r) {
      int row = fm * 16 + lk * 4 + r;
      float s = 0.f, sq = 0.f;
#pragma unroll
      for (int j = 0; j < 8; ++j) {
        s += sScr[row * 16 + j * 2];
        sq += sScr[row * 16 + j * 2 + 1];
      }
      float mu = s * (1.f / 256.f);
      float var = sq * (1.f / 256.f) - mu * mu;
      float rstd = rsqrtf(var + 1e-5f);
      float y0 = (acc[fm][0][r] - mu) * rstd * gv0 + bv0;
      float y1 = (acc[fm][1][r] - mu) * rstd * gv1 + bv1;
      sAttn[row * 264 + wn + lr] = f2bf(y0);        // safe: all MFMAs done
      sAttn[row * 264 + wn + 16 + lr] = f2bf(y1);
    }
  __syncthreads();
  // coalesced store to cat[:,256:512]
#pragma unroll
  for (int i = 0; i < 4; ++i) {
    int idx = t + i * 512;       // 0..2047 -> row(6b) x c16(5b)
    int row = idx >> 5, c16 = idx & 31;
    uint4 val = *reinterpret_cast<const uint4*>(&sAttn[row * 264 + c16 * 8]);
    *reinterpret_cast<uint4*>(cat + (size_t)(m0 + row) * 512 + 256 + c16 * 8) = val;
  }
}

// ---- FUSED: MLP2 + LN2 + transpose + residual -> out ------------------------
// BM=128, N=256 full, K=512; grid 256, 512 threads (8 waves 2m x 4n)
__global__ __launch_bounds__(512) void mlp2_tail_kernel(
    const u16* __restrict__ hidden, const u16* __restrict__ W2T,
    const float* __restrict__ g2, const float* __restrict__ b2,
    const float* __restrict__ x, float* __restrict__ out) {
  __shared__ alignas(16) char smem[16384 + 32768 + 4096 + 2048];
  u16* sA = (u16*)smem;                   // [128][64]
  u16* sB = (u16*)(smem + 16384);         // [256][64]
  float* scr = (float*)(smem + 49152);    // [128][4][2]
  float* sG = (float*)(smem + 53248);     // g2|b2
  float* T = (float*)smem;                // [64][129] overlay (33KB), post-GEMM
  const int t = threadIdx.x;
  const int m0 = blockIdx.x * 128;
  const int b = m0 >> 12, l0 = m0 & 4095;
  if (t < 256) { sG[t] = g2[t]; sG[256 + t] = b2[t]; }
  const int w = t >> 6, lane = t & 63;
  const int wm = (w >> 2) * 64, wn = (w & 3) * 64;
  const int lr = lane & 15, lk = lane >> 4;
  f32x4 acc[4][4] = {};
  for (int kt = 0; kt < 8; ++kt) {
    __syncthreads();
#pragma unroll
    for (int i = 0; i < 2; ++i) {
      int id = t + i * 512, row = id >> 3, chn = (id & 7) << 3;
      GLDS16(hidden + (size_t)(m0 + row) * 512 + kt * 64 + chn, sA + id * 8);
    }
#pragma unroll
    for (int i = 0; i < 4; ++i) {
      int id = t + i * 512, row = id >> 3, chn = (id & 7) << 3;
      GLDS16(W2T + (size_t)row * 512 + kt * 64 + chn, sB + id * 8);
    }
    __syncthreads();
    bf16x8 af[4][2], bfr[4][2];
#pragma unroll
    for (int f = 0; f < 4; ++f) {
#pragma unroll
      for (int ks = 0; ks < 2; ++ks) {
        af[f][ks] = *reinterpret_cast<const bf16x8*>(
            &sA[(wm + f * 16 + lr) * 64 + ks * 32 + lk * 8]);
        bfr[f][ks] = *reinterpret_cast<const bf16x8*>(
            &sB[(wn + f * 16 + lr) * 64 + ks * 32 + lk * 8]);
      }
    }
#pragma unroll
    for (int ks = 0; ks < 2; ++ks)
#pragma unroll
      for (int fm = 0; fm < 4; ++fm)
#pragma unroll
        for (int fn = 0; fn < 4; ++fn)
          acc[fm][fn] = __builtin_amdgcn_mfma_f32_16x16x32_bf16(
              af[fm][ks], bfr[fn][ks], acc[fm][fn], 0, 0, 0);
  }
  // ---- LN2 cross-wave ----
#pragma unroll
  for (int fm = 0; fm < 4; ++fm)
#pragma unroll
    for (int r = 0; r < 4; ++r) {
      float s = 0.f, sq = 0.f;
#pragma unroll
      for (int fn = 0; fn < 4; ++fn) {
        float a = acc[fm][fn][r];
        s += a; sq += a * a;
      }
#pragma unroll
      for (int off = 1; off < 16; off <<= 1) {
        s += __shfl_xor(s, off);
        sq += __shfl_xor(sq, off);
      }
      if (lr == 0) {
        int row = wm + fm * 16 + lk * 4 + r;
        scr[row * 8 + (w & 3) * 2] = s;
        scr[row * 8 + (w & 3) * 2 + 1] = sq;
      }
    }
  __syncthreads();
  float gvs[4], bvs[4];
#pragma unroll
  for (int fn = 0; fn < 4; ++fn) {
    gvs[fn] = sG[wn + fn * 16 + lr];
    bvs[fn] = sG[256 + wn + fn * 16 + lr];
  }
#pragma unroll
  for (int fm = 0; fm < 4; ++fm)
#pragma unroll
    for (int r = 0; r < 4; ++r) {
      int row = wm + fm * 16 + lk * 4 + r;
      float s = 0.f, sq = 0.f;
#pragma unroll
      for (int j = 0; j < 4; ++j) {
        s += scr[row * 8 + j * 2];
        sq += scr[row * 8 + j * 2 + 1];
      }
      float mu = s * (1.f / 256.f);
      float var = sq * (1.f / 256.f) - mu * mu;
      float rstd = rsqrtf(var + 1e-5f);
#pragma unroll
      for (int fn = 0; fn < 4; ++fn)
        acc[fm][fn][r] = (acc[fm][fn][r] - mu) * rstd * gvs[fn] + bvs[fn];
    }
  __syncthreads();   // all waves done with sA/sB + scr -> T overlay safe
  // ---- transpose chunks of 64 cols + residual add ----
  for (int cc = 0; cc < 4; ++cc) {
    if ((w & 3) == cc) {
#pragma unroll
      for (int fm = 0; fm < 4; ++fm)
#pragma unroll
        for (int fn = 0; fn < 4; ++fn)
#pragma unroll
          for (int r = 0; r < 4; ++r)
            T[(fn * 16 + lr) * 129 + wm + fm * 16 + lk * 4 + r] = acc[fm][fn][r];
    }
    __syncthreads();
#pragma unroll
    for (int i = 0; i < 4; ++i) {
      int idx = t + i * 512;            // 0..2047
      int cT = idx >> 5, lq = (idx & 31) * 4;
      int cg = cc * 64 + cT;
      size_t o = ((size_t)b * 256 + cg) * 4096 + l0 + lq;
      float4 xv = *reinterpret_cast<const float4*>(x + o);
      float4 ov;
      ov.x = xv.x + T[cT * 129 + lq];
      ov.y = xv.y + T[cT * 129 + lq + 1];
      ov.z = xv.z + T[cT * 129 + lq + 2];
      ov.w = xv.w + T[cT * 129 + lq + 3];
      *reinterpret_cast<float4*>(out + o) = ov;
    }
    __syncthreads();
  }
}

extern "C" void kernel_launch(void* const* d_in, const int* in_sizes, int n_in,
                              void* d_out, int out_size, void* d_ws, size_t ws_size,
                              hipStream_t stream) {
  (void)in_sizes; (void)n_in; (void)out_size; (void)ws_size;
  const float* x = (const float*)d_in[0];
  const float* srcp = (const float*)d_in[1];
  const float* Wq = (const float*)d_in[2];
  const float* Wk = (const float*)d_in[3];
  const float* Wv = (const float*)d_in[4];
  const float* Wm = (const float*)d_in[5];
  const float* W1 = (const float*)d_in[6];
  const float* W2 = (const float*)d_in[7];
  const float* g1 = (const float*)d_in[8];
  const float* b1 = (const float*)d_in[9];
  const float* g2 = (const float*)d_in[10];
  const float* b2 = (const float*)d_in[11];
  float* out = (float*)d_out;
  char* ws = (char*)d_ws;

  u16* wqt = (u16*)(ws + OFF_WQ);
  u16* wkvt = (u16*)(ws + OFF_WK);
  u16* wkt = (u16*)(ws + OFF_WK);
  u16* wvt = (u16*)(ws + OFF_WV);
  u16* wmt = (u16*)(ws + OFF_WM);
  u16* w1t = (u16*)(ws + OFF_W1);
  u16* w2t = (u16*)(ws + OFF_W2);
  u16* cat = (u16*)(ws + OFF_CAT);
  u16* ssb = (u16*)(ws + OFF_SSB);
  u16* Qb = (u16*)(ws + OFF_Q);
  u16* kvproj = (u16*)(ws + OFF_KVPROJ);
  float* KVb = (float*)(ws + OFF_KV);
  float* KSb = (float*)(ws + OFF_KS);
  float* KVp = (float*)(ws + OFF_KVP);
  float* KSp = (float*)(ws + OFF_KSP);
  u16* hidden = kvproj;  // reuse after kv_partial consumed kvproj

  dim3 blk(256);
  wprep_all_kernel<<<dim3(640), blk, 0, stream>>>(Wq, Wk, Wv, Wm, W1, W2,
                                                  wqt, wkt, wvt, wmt, w1t, w2t);
  transpose_in_kernel<<<dim3(128, 8, 16), blk, 0, stream>>>(x, srcp, cat, ssb);
  gemm_kernel<1><<<dim3(2, 256), blk, 0, stream>>>(cat, 512, wqt, 256, Qb, 256);
  gemm_kernel<4><<<dim3(4, 256), blk, 0, stream>>>(ssb, 256, wkvt, 256, kvproj, 512);
  kv_partial_kernel<<<dim3(64, 8), blk, 0, stream>>>(kvproj, KVp, KSp);
  kv_reduce_kernel<<<dim3(264), blk, 0, stream>>>(KVp, KSp, KVb, KSb);
  attn_wm_ln1_kernel<<<dim3(512), dim3(512), 0, stream>>>(Qb, KVb, KSb, wmt,
                                                          g1, b1, cat);
  gemm_kernel<3><<<dim3(4, 256), blk, 0, stream>>>(cat, 512, w1t, 512, hidden, 512);
  mlp2_tail_kernel<<<dim3(256), dim3(512), 0, stream>>>(hidden, w2t, g2, b2, x, out);
}

// Round 4
// 189.769 us; speedup vs baseline: 1.1521x; 1.0230x over previous
//
#include <hip/hip_runtime.h>

typedef unsigned short u16;
typedef __bf16 bf16x8 __attribute__((ext_vector_type(8)));
typedef float f32x4 __attribute__((ext_vector_type(4)));

__device__ __forceinline__ u16 f2bf(float f) {
  unsigned int u = __float_as_uint(f);
  u += 0x7fffu + ((u >> 16) & 1u);
  return (u16)(u >> 16);
}
__device__ __forceinline__ float bf2f(u16 v) {
  return __uint_as_float(((unsigned)v) << 16);
}

#define GLDS16(gp, lp)                                                   \
  __builtin_amdgcn_global_load_lds(                                      \
      (const __attribute__((address_space(1))) unsigned int*)(gp),       \
      (__attribute__((address_space(3))) unsigned int*)(lp), 16, 0, 0)

// B=8, C=256, L=4096, M=32768, NHEAD=8, dim=32
// ws layout (bytes)
#define OFF_WQ     0u
#define OFF_WK     131072u     /* wkvt rows 0:256 */
#define OFF_WV     262144u
#define OFF_WM     393216u
#define OFF_W1     524288u
#define OFF_W2     1048576u
#define OFF_CAT    1310720u    /* u16 [M][512]: 0:256 xs, 256:512 ln1 */
#define OFF_SSB    34865152u   /* u16 [M][256] ss_bf16 ; later Qs (Q*Z) */
#define OFF_Q      51642368u   /* u16 [M][256] Q bf16 */
#define OFF_KVPROJ 68419584u   /* u16 [M][512] K|vals bf16 ; later hidden */
#define OFF_KV     152305664u  /* f32 [64][32][32] */
#define OFF_KS     152567808u  /* f32 [64][32] */
#define OFF_KVP    152576000u  /* f32 [8][64][32][32] partials ; later wcomb */
#define OFF_KSP    154673152u  /* f32 [8][64][32] partials */

// ---- transposes fp32 [C,L] -> bf16 [L,C] ------------------------------------
__global__ __launch_bounds__(256) void transpose_in_kernel(
    const float* __restrict__ x, const float* __restrict__ srcp,
    u16* __restrict__ cat, u16* __restrict__ ssb) {
  __shared__ float s[32][33];
  int z = blockIdx.z;
  const float* src = z < 8 ? x : srcp;
  u16* dst = z < 8 ? cat : ssb;
  int dstride = z < 8 ? 512 : 256;
  int b = z & 7;
  int lt = blockIdx.x * 32, ct = blockIdx.y * 32;
  int tx = threadIdx.x & 31, ty = threadIdx.x >> 5;
#pragma unroll
  for (int i = 0; i < 4; ++i)
    s[ty + i * 8][tx] = src[((size_t)b * 256 + ct + ty + i * 8) * 4096 + lt + tx];
  __syncthreads();
#pragma unroll
  for (int i = 0; i < 4; ++i)
    dst[((size_t)b * 4096 + lt + ty + i * 8) * dstride + ct + tx] = f2bf(s[tx][ty + i * 8]);
}

// ---- weight prep: fp32 [K,N] -> bf16 [N,K], all weights one dispatch --------
__global__ __launch_bounds__(256) void wprep_all_kernel(
    const float* __restrict__ Wq, const float* __restrict__ Wk,
    const float* __restrict__ Wv, const float* __restrict__ Wm,
    const float* __restrict__ W1, const float* __restrict__ W2,
    u16* __restrict__ dq, u16* __restrict__ dk, u16* __restrict__ dv,
    u16* __restrict__ dm, u16* __restrict__ d1, u16* __restrict__ d2) {
  __shared__ float s[32][33];
  int bid = blockIdx.x;
  const float* src; u16* dst; int Kd, Nd, t;
  if (bid < 64)       { src = Wq; dst = dq; Kd = 256; Nd = 256; t = bid; }
  else if (bid < 128) { src = Wk; dst = dk; Kd = 256; Nd = 256; t = bid - 64; }
  else if (bid < 192) { src = Wv; dst = dv; Kd = 256; Nd = 256; t = bid - 128; }
  else if (bid < 256) { src = Wm; dst = dm; Kd = 256; Nd = 256; t = bid - 192; }
  else if (bid < 512) { src = W1; dst = d1; Kd = 512; Nd = 512; t = bid - 256; }
  else                { src = W2; dst = d2; Kd = 512; Nd = 256; t = bid - 512; }
  int ntn = Nd >> 5;
  int kt = (t / ntn) * 32, nt = (t % ntn) * 32;
  int tx = threadIdx.x & 31, ty = threadIdx.x >> 5;
#pragma unroll
  for (int i = 0; i < 4; ++i)
    s[ty + i * 8][tx] = src[(size_t)(kt + ty + i * 8) * Nd + nt + tx];
  __syncthreads();
#pragma unroll
  for (int i = 0; i < 4; ++i)
    dst[(size_t)(nt + ty + i * 8) * Kd + kt + tx] = f2bf(s[tx][ty + i * 8]);
}

// ---- bf16 MFMA GEMM, 128x128 tile, 4 waves, gload_lds staging ---------------
// EPI: 1 elu+1 bf16 | 3 relu bf16 | 4 fused kv (col<256 elu+1, else /4096) bf16
template <int EPI>
__global__ __launch_bounds__(256) void gemm_kernel(
    const u16* __restrict__ A, int lda, const u16* __restrict__ Wt, int K,
    u16* __restrict__ outp, int ldo) {
  __shared__ alignas(16) u16 sA[128 * 64];
  __shared__ alignas(16) u16 sB[128 * 64];
  const int tid = threadIdx.x;
  const int m0 = blockIdx.y * 128, n0 = blockIdx.x * 128;
  const int w = tid >> 6, lane = tid & 63;
  const int wm = (w >> 1) * 64, wn = (w & 1) * 64;
  const int lr = lane & 15, lk = lane >> 4;
  f32x4 acc[4][4] = {};
  const int srow = tid >> 3, sch = (tid & 7) << 3;
  const u16* ga = A + (size_t)(m0 + srow) * lda + sch;
  const u16* gb = Wt + (size_t)(n0 + srow) * K + sch;

  const int nkt = K >> 6;
  for (int kt = 0; kt < nkt; ++kt) {
    __syncthreads();
#pragma unroll
    for (int i = 0; i < 4; ++i) {
      GLDS16(ga + (size_t)i * 32 * lda + kt * 64, sA + (tid + i * 256) * 8);
      GLDS16(gb + (size_t)i * 32 * K + kt * 64, sB + (tid + i * 256) * 8);
    }
    __syncthreads();
    bf16x8 af[4][2], bfr[4][2];
#pragma unroll
    for (int f = 0; f < 4; ++f) {
#pragma unroll
      for (int ks = 0; ks < 2; ++ks) {
        af[f][ks] = *reinterpret_cast<const bf16x8*>(
            &sA[(wm + f * 16 + lr) * 64 + ks * 32 + lk * 8]);
        bfr[f][ks] = *reinterpret_cast<const bf16x8*>(
            &sB[(wn + f * 16 + lr) * 64 + ks * 32 + lk * 8]);
      }
    }
#pragma unroll
    for (int ks = 0; ks < 2; ++ks)
#pragma unroll
      for (int fm = 0; fm < 4; ++fm)
#pragma unroll
        for (int fn = 0; fn < 4; ++fn)
          acc[fm][fn] = __builtin_amdgcn_mfma_f32_16x16x32_bf16(
              af[fm][ks], bfr[fn][ks], acc[fm][fn], 0, 0, 0);
  }

  const int r0 = (lane >> 4) * 4, c0 = lane & 15;
#pragma unroll
  for (int fm = 0; fm < 4; ++fm) {
#pragma unroll
    for (int fn = 0; fn < 4; ++fn) {
      int gr = m0 + wm + fm * 16 + r0;
      int gc = n0 + wn + fn * 16 + c0;
#pragma unroll
      for (int r = 0; r < 4; ++r) {
        float v = acc[fm][fn][r];
        if (EPI == 1) v = v > 0.f ? v + 1.f : __expf(v);
        if (EPI == 3) v = v > 0.f ? v : 0.f;
        if (EPI == 4) v = (gc < 256) ? (v > 0.f ? v + 1.f : __expf(v)) : v * (1.f / 4096.f);
        outp[(size_t)(gr + r) * ldo + gc] = f2bf(v);
      }
    }
  }
}

// ---- KV partial over L-slices (reads bf16 kvproj [M][512]) ------------------
__global__ __launch_bounds__(256) void kv_partial_kernel(
    const u16* __restrict__ KVproj, float* __restrict__ KVp,
    float* __restrict__ KSp) {
  __shared__ alignas(16) float sK[64][32];
  __shared__ alignas(16) float sV[64][32];
  const int bh = blockIdx.x, sl = blockIdx.y;
  const int b = bh >> 3, h = bh & 7;
  const int t = threadIdx.x;
  const int lrow = t >> 2, lcol = (t & 3) * 8;
  const int d = t >> 3, vg = (t & 7) * 4;
  float a0 = 0, a1 = 0, a2 = 0, a3 = 0, ks = 0;
  for (int lt = 0; lt < 512; lt += 64) {
    __syncthreads();
    size_t roff = ((size_t)b * 4096 + sl * 512 + lt + lrow) * 512 + h * 32 + lcol;
    uint4 kq = *reinterpret_cast<const uint4*>(KVproj + roff);
    uint4 vq = *reinterpret_cast<const uint4*>(KVproj + roff + 256);
    float* dk = &sK[lrow][lcol];
    float* dv = &sV[lrow][lcol];
#pragma unroll
    for (int j = 0; j < 4; ++j) {
      unsigned uk = ((const unsigned*)&kq)[j];
      unsigned uv = ((const unsigned*)&vq)[j];
      dk[2 * j] = __uint_as_float(uk << 16);
      dk[2 * j + 1] = __uint_as_float(uk & 0xffff0000u);
      dv[2 * j] = __uint_as_float(uv << 16);
      dv[2 * j + 1] = __uint_as_float(uv & 0xffff0000u);
    }
    __syncthreads();
#pragma unroll 8
    for (int i = 0; i < 64; ++i) {
      float kd = sK[i][d];
      a0 += kd * sV[i][vg + 0];
      a1 += kd * sV[i][vg + 1];
      a2 += kd * sV[i][vg + 2];
      a3 += kd * sV[i][vg + 3];
      ks += kd;
    }
  }
  float* o = KVp + (size_t)sl * 65536 + bh * 1024 + d * 32 + vg;
  o[0] = a0; o[1] = a1; o[2] = a2; o[3] = a3;
  if ((t & 7) == 0) KSp[(size_t)sl * 2048 + bh * 32 + d] = ks;
}

__global__ __launch_bounds__(256) void kv_reduce_kernel(
    const float* __restrict__ KVp, const float* __restrict__ KSp,
    float* __restrict__ KV, float* __restrict__ Ksum) {
  int gid = blockIdx.x * 256 + threadIdx.x;
  if (gid < 65536) {
    float s = 0;
#pragma unroll
    for (int i = 0; i < 8; ++i) s += KVp[(size_t)i * 65536 + gid];
    KV[gid] = s;
  } else if (gid - 65536 < 2048) {
    int j = gid - 65536;
    float s = 0;
#pragma unroll
    for (int i = 0; i < 8; ++i) s += KSp[(size_t)i * 2048 + j];
    Ksum[j] = s;
  }
}

// ---- W_comb[b][n][k] = sum_v KV[b,h(k),d(k),v] * WmT[n][h*32+v] -> bf16 -----
__global__ __launch_bounds__(256) void wcomb_kernel(
    const float* __restrict__ KVb, const u16* __restrict__ wmt,
    u16* __restrict__ wc) {
  const int bid = blockIdx.x;  // 0..2047
  const int b = bid >> 8, n = bid & 255;
  const int k = threadIdx.x, h = k >> 5, d = k & 31;
  const float* kv = KVb + ((size_t)b * 8 + h) * 1024 + d * 32;
  const u16* wm = wmt + (size_t)n * 256 + h * 32;
  float s = 0.f;
#pragma unroll
  for (int v = 0; v < 32; ++v) s += kv[v] * bf2f(wm[v]);
  wc[((size_t)b * 256 + n) * 256 + k] = f2bf(s);
}

// ---- Qs[l,c] = Q[l,c] * (4096 / (sum_d Q[l,h(c),d]*Ksum[h(c),d] + eps)) -----
__global__ __launch_bounds__(256) void qscale_kernel(
    const u16* __restrict__ Qb, const float* __restrict__ KSb,
    u16* __restrict__ Qs) {
  const int row = blockIdx.x * 4 + (threadIdx.x >> 6);
  const int lane = threadIdx.x & 63;
  const int b = row >> 12;
  uint2 qv = *reinterpret_cast<const uint2*>(Qb + (size_t)row * 256 + lane * 4);
  float q0 = bf2f((u16)(qv.x & 0xffff)), q1 = bf2f((u16)(qv.x >> 16));
  float q2 = bf2f((u16)(qv.y & 0xffff)), q3 = bf2f((u16)(qv.y >> 16));
  float4 ks = *reinterpret_cast<const float4*>(KSb + b * 256 + lane * 4);
  float d = q0 * ks.x + q1 * ks.y + q2 * ks.z + q3 * ks.w;
  d += __shfl_xor(d, 1);
  d += __shfl_xor(d, 2);
  d += __shfl_xor(d, 4);   // 8-lane group = one head (32 cols)
  float z = 4096.f / (d + 1e-6f);
  uint2 o;
  o.x = (unsigned)f2bf(q0 * z) | ((unsigned)f2bf(q1 * z) << 16);
  o.y = (unsigned)f2bf(q2 * z) | ((unsigned)f2bf(q3 * z) << 16);
  *reinterpret_cast<uint2*>(Qs + (size_t)row * 256 + lane * 4) = o;
}

// ---- FUSED: msg = Qs @ Wcomb[b]  + LN1 -> cat[:,256:512] bf16 ---------------
// BM=128, N=256 full, K=256; grid 256, 512 threads (8 waves 2m x 4n)
__global__ __launch_bounds__(512) void msgwm_ln1_kernel(
    const u16* __restrict__ Qs, const u16* __restrict__ wc,
    const float* __restrict__ g1, const float* __restrict__ b1,
    u16* __restrict__ cat) {
  __shared__ alignas(16) char smem[49152 + 4096 + 2048];
  u16* sA = (u16*)smem;                   // [128][64]
  u16* sB = (u16*)(smem + 16384);         // [256][64]
  float* scr = (float*)(smem + 49152);    // [128][8]
  float* sG = (float*)(smem + 53248);     // g1|b1
  u16* T = (u16*)smem;                    // [64][264] overlay post-GEMM (33.8KB)
  const int t = threadIdx.x;
  const int m0 = blockIdx.x * 128;
  const int b = m0 >> 12;
  const u16* Bw = wc + (size_t)b * 65536;
  if (t < 256) { sG[t] = g1[t]; sG[256 + t] = b1[t]; }
  const int w = t >> 6, lane = t & 63;
  const int wm = (w >> 2) * 64, wn = (w & 3) * 64;
  const int lr = lane & 15, lk = lane >> 4;
  f32x4 acc[4][4] = {};
  for (int kt = 0; kt < 4; ++kt) {
    __syncthreads();
#pragma unroll
    for (int i = 0; i < 2; ++i) {
      int id = t + i * 512, row = id >> 3, chn = (id & 7) << 3;
      GLDS16(Qs + (size_t)(m0 + row) * 256 + kt * 64 + chn, sA + id * 8);
    }
#pragma unroll
    for (int i = 0; i < 4; ++i) {
      int id = t + i * 512, row = id >> 3, chn = (id & 7) << 3;
      GLDS16(Bw + (size_t)row * 256 + kt * 64 + chn, sB + id * 8);
    }
    __syncthreads();
    bf16x8 af[4][2], bfr[4][2];
#pragma unroll
    for (int f = 0; f < 4; ++f) {
#pragma unroll
      for (int ks = 0; ks < 2; ++ks) {
        af[f][ks] = *reinterpret_cast<const bf16x8*>(
            &sA[(wm + f * 16 + lr) * 64 + ks * 32 + lk * 8]);
        bfr[f][ks] = *reinterpret_cast<const bf16x8*>(
            &sB[(wn + f * 16 + lr) * 64 + ks * 32 + lk * 8]);
      }
    }
#pragma unroll
    for (int ks = 0; ks < 2; ++ks)
#pragma unroll
      for (int fm = 0; fm < 4; ++fm)
#pragma unroll
        for (int fn = 0; fn < 4; ++fn)
          acc[fm][fn] = __builtin_amdgcn_mfma_f32_16x16x32_bf16(
              af[fm][ks], bfr[fn][ks], acc[fm][fn], 0, 0, 0);
  }
  // ---- LN1 cross-wave ----
#pragma unroll
  for (int fm = 0; fm < 4; ++fm)
#pragma unroll
    for (int r = 0; r < 4; ++r) {
      float s = 0.f, sq = 0.f;
#pragma unroll
      for (int fn = 0; fn < 4; ++fn) {
        float a = acc[fm][fn][r];
        s += a; sq += a * a;
      }
#pragma unroll
      for (int off = 1; off < 16; off <<= 1) {
        s += __shfl_xor(s, off);
        sq += __shfl_xor(sq, off);
      }
      if (lr == 0) {
        int row = wm + fm * 16 + lk * 4 + r;
        scr[row * 8 + (w & 3) * 2] = s;
        scr[row * 8 + (w & 3) * 2 + 1] = sq;
      }
    }
  __syncthreads();
  float gvs[4], bvs[4];
#pragma unroll
  for (int fn = 0; fn < 4; ++fn) {
    gvs[fn] = sG[wn + fn * 16 + lr];
    bvs[fn] = sG[256 + wn + fn * 16 + lr];
  }
#pragma unroll
  for (int fm = 0; fm < 4; ++fm)
#pragma unroll
    for (int r = 0; r < 4; ++r) {
      int row = wm + fm * 16 + lk * 4 + r;
      float s = 0.f, sq = 0.f;
#pragma unroll
      for (int j = 0; j < 4; ++j) {
        s += scr[row * 8 + j * 2];
        sq += scr[row * 8 + j * 2 + 1];
      }
      float mu = s * (1.f / 256.f);
      float var = sq * (1.f / 256.f) - mu * mu;
      float rstd = rsqrtf(var + 1e-5f);
#pragma unroll
      for (int fn = 0; fn < 4; ++fn)
        acc[fm][fn][r] = (acc[fm][fn][r] - mu) * rstd * gvs[fn] + bvs[fn];
    }
  // ---- restage through LDS, coalesced bf16 store to cat[:,256:512] ----
  for (int hh = 0; hh < 2; ++hh) {
    __syncthreads();
    if ((w >> 2) == hh) {
#pragma unroll
      for (int fm = 0; fm < 4; ++fm)
#pragma unroll
        for (int fn = 0; fn < 4; ++fn)
#pragma unroll
          for (int r = 0; r < 4; ++r)
            T[(fm * 16 + lk * 4 + r) * 264 + wn + fn * 16 + lr] =
                f2bf(acc[fm][fn][r]);
    }
    __syncthreads();
#pragma unroll
    for (int i = 0; i < 4; ++i) {
      int idx = t + i * 512;             // 0..2047: row(6b) x c16(5b)
      int row = idx >> 5, c16 = idx & 31;
      uint4 val = *reinterpret_cast<const uint4*>(&T[row * 264 + c16 * 8]);
      *reinterpret_cast<uint4*>(
          cat + (size_t)(m0 + hh * 64 + row) * 512 + 256 + c16 * 8) = val;
    }
  }
}

// ---- FUSED: MLP2 + LN2 + transpose + residual -> out ------------------------
__global__ __launch_bounds__(512) void mlp2_tail_kernel(
    const u16* __restrict__ hidden, const u16* __restrict__ W2T,
    const float* __restrict__ g2, const float* __restrict__ b2,
    const float* __restrict__ x, float* __restrict__ out) {
  __shared__ alignas(16) char smem[16384 + 32768 + 4096 + 2048];
  u16* sA = (u16*)smem;                   // [128][64]
  u16* sB = (u16*)(smem + 16384);         // [256][64]
  float* scr = (float*)(smem + 49152);    // [128][8]
  float* sG = (float*)(smem + 53248);     // g2|b2
  float* T = (float*)smem;                // [64][129] overlay, post-GEMM
  const int t = threadIdx.x;
  const int m0 = blockIdx.x * 128;
  const int b = m0 >> 12, l0 = m0 & 4095;
  if (t < 256) { sG[t] = g2[t]; sG[256 + t] = b2[t]; }
  const int w = t >> 6, lane = t & 63;
  const int wm = (w >> 2) * 64, wn = (w & 3) * 64;
  const int lr = lane & 15, lk = lane >> 4;
  f32x4 acc[4][4] = {};
  for (int kt = 0; kt < 8; ++kt) {
    __syncthreads();
#pragma unroll
    for (int i = 0; i < 2; ++i) {
      int id = t + i * 512, row = id >> 3, chn = (id & 7) << 3;
      GLDS16(hidden + (size_t)(m0 + row) * 512 + kt * 64 + chn, sA + id * 8);
    }
#pragma unroll
    for (int i = 0; i < 4; ++i) {
      int id = t + i * 512, row = id >> 3, chn = (id & 7) << 3;
      GLDS16(W2T + (size_t)row * 512 + kt * 64 + chn, sB + id * 8);
    }
    __syncthreads();
    bf16x8 af[4][2], bfr[4][2];
#pragma unroll
    for (int f = 0; f < 4; ++f) {
#pragma unroll
      for (int ks = 0; ks < 2; ++ks) {
        af[f][ks] = *reinterpret_cast<const bf16x8*>(
            &sA[(wm + f * 16 + lr) * 64 + ks * 32 + lk * 8]);
        bfr[f][ks] = *reinterpret_cast<const bf16x8*>(
            &sB[(wn + f * 16 + lr) * 64 + ks * 32 + lk * 8]);
      }
    }
#pragma unroll
    for (int ks = 0; ks < 2; ++ks)
#pragma unroll
      for (int fm = 0; fm < 4; ++fm)
#pragma unroll
        for (int fn = 0; fn < 4; ++fn)
          acc[fm][fn] = __builtin_amdgcn_mfma_f32_16x16x32_bf16(
              af[fm][ks], bfr[fn][ks], acc[fm][fn], 0, 0, 0);
  }
  // ---- LN2 cross-wave ----
#pragma unroll
  for (int fm = 0; fm < 4; ++fm)
#pragma unroll
    for (int r = 0; r < 4; ++r) {
      float s = 0.f, sq = 0.f;
#pragma unroll
      for (int fn = 0; fn < 4; ++fn) {
        float a = acc[fm][fn][r];
        s += a; sq += a * a;
      }
#pragma unroll
      for (int off = 1; off < 16; off <<= 1) {
        s += __shfl_xor(s, off);
        sq += __shfl_xor(sq, off);
      }
      if (lr == 0) {
        int row = wm + fm * 16 + lk * 4 + r;
        scr[row * 8 + (w & 3) * 2] = s;
        scr[row * 8 + (w & 3) * 2 + 1] = sq;
      }
    }
  __syncthreads();
  float gvs[4], bvs[4];
#pragma unroll
  for (int fn = 0; fn < 4; ++fn) {
    gvs[fn] = sG[wn + fn * 16 + lr];
    bvs[fn] = sG[256 + wn + fn * 16 + lr];
  }
#pragma unroll
  for (int fm = 0; fm < 4; ++fm)
#pragma unroll
    for (int r = 0; r < 4; ++r) {
      int row = wm + fm * 16 + lk * 4 + r;
      float s = 0.f, sq = 0.f;
#pragma unroll
      for (int j = 0; j < 4; ++j) {
        s += scr[row * 8 + j * 2];
        sq += scr[row * 8 + j * 2 + 1];
      }
      float mu = s * (1.f / 256.f);
      float var = sq * (1.f / 256.f) - mu * mu;
      float rstd = rsqrtf(var + 1e-5f);
#pragma unroll
      for (int fn = 0; fn < 4; ++fn)
        acc[fm][fn][r] = (acc[fm][fn][r] - mu) * rstd * gvs[fn] + bvs[fn];
    }
  __syncthreads();
  // ---- transpose chunks of 64 cols + residual add ----
  for (int cc = 0; cc < 4; ++cc) {
    if ((w & 3) == cc) {
#pragma unroll
      for (int fm = 0; fm < 4; ++fm)
#pragma unroll
        for (int fn = 0; fn < 4; ++fn)
#pragma unroll
          for (int r = 0; r < 4; ++r)
            T[(fn * 16 + lr) * 129 + wm + fm * 16 + lk * 4 + r] = acc[fm][fn][r];
    }
    __syncthreads();
#pragma unroll
    for (int i = 0; i < 4; ++i) {
      int idx = t + i * 512;
      int cT = idx >> 5, lq = (idx & 31) * 4;
      int cg = cc * 64 + cT;
      size_t o = ((size_t)b * 256 + cg) * 4096 + l0 + lq;
      float4 xv = *reinterpret_cast<const float4*>(x + o);
      float4 ov;
      ov.x = xv.x + T[cT * 129 + lq];
      ov.y = xv.y + T[cT * 129 + lq + 1];
      ov.z = xv.z + T[cT * 129 + lq + 2];
      ov.w = xv.w + T[cT * 129 + lq + 3];
      *reinterpret_cast<float4*>(out + o) = ov;
    }
    __syncthreads();
  }
}

extern "C" void kernel_launch(void* const* d_in, const int* in_sizes, int n_in,
                              void* d_out, int out_size, void* d_ws, size_t ws_size,
                              hipStream_t stream) {
  (void)in_sizes; (void)n_in; (void)out_size; (void)ws_size;
  const float* x = (const float*)d_in[0];
  const float* srcp = (const float*)d_in[1];
  const float* Wq = (const float*)d_in[2];
  const float* Wk = (const float*)d_in[3];
  const float* Wv = (const float*)d_in[4];
  const float* Wm = (const float*)d_in[5];
  const float* W1 = (const float*)d_in[6];
  const float* W2 = (const float*)d_in[7];
  const float* g1 = (const float*)d_in[8];
  const float* b1 = (const float*)d_in[9];
  const float* g2 = (const float*)d_in[10];
  const float* b2 = (const float*)d_in[11];
  float* out = (float*)d_out;
  char* ws = (char*)d_ws;

  u16* wqt = (u16*)(ws + OFF_WQ);
  u16* wkvt = (u16*)(ws + OFF_WK);
  u16* wkt = (u16*)(ws + OFF_WK);
  u16* wvt = (u16*)(ws + OFF_WV);
  u16* wmt = (u16*)(ws + OFF_WM);
  u16* w1t = (u16*)(ws + OFF_W1);
  u16* w2t = (u16*)(ws + OFF_W2);
  u16* cat = (u16*)(ws + OFF_CAT);
  u16* ssb = (u16*)(ws + OFF_SSB);
  u16* Qb = (u16*)(ws + OFF_Q);
  u16* kvproj = (u16*)(ws + OFF_KVPROJ);
  float* KVb = (float*)(ws + OFF_KV);
  float* KSb = (float*)(ws + OFF_KS);
  float* KVp = (float*)(ws + OFF_KVP);
  float* KSp = (float*)(ws + OFF_KSP);
  u16* hidden = kvproj;      // reuse after kv_partial consumed kvproj
  u16* Qs = ssb;             // reuse after kv gemm consumed ssb
  u16* wcombT = (u16*)(ws + OFF_KVP);  // reuse partials after kv_reduce

  dim3 blk(256);
  wprep_all_kernel<<<dim3(640), blk, 0, stream>>>(Wq, Wk, Wv, Wm, W1, W2,
                                                  wqt, wkt, wvt, wmt, w1t, w2t);
  transpose_in_kernel<<<dim3(128, 8, 16), blk, 0, stream>>>(x, srcp, cat, ssb);
  gemm_kernel<4><<<dim3(4, 256), blk, 0, stream>>>(ssb, 256, wkvt, 256, kvproj, 512);
  gemm_kernel<1><<<dim3(2, 256), blk, 0, stream>>>(cat, 512, wqt, 256, Qb, 256);
  kv_partial_kernel<<<dim3(64, 8), blk, 0, stream>>>(kvproj, KVp, KSp);
  kv_reduce_kernel<<<dim3(264), blk, 0, stream>>>(KVp, KSp, KVb, KSb);
  wcomb_kernel<<<dim3(2048), blk, 0, stream>>>(KVb, wmt, wcombT);
  qscale_kernel<<<dim3(8192), blk, 0, stream>>>(Qb, KSb, Qs);
  msgwm_ln1_kernel<<<dim3(256), dim3(512), 0, stream>>>(Qs, wcombT, g1, b1, cat);
  gemm_kernel<3><<<dim3(4, 256), blk, 0, stream>>>(cat, 512, w1t, 512, hidden, 512);
  mlp2_tail_kernel<<<dim3(256), dim3(512), 0, stream>>>(hidden, w2t, g2, b2, x, out);
}

// Round 5
// 175.759 us; speedup vs baseline: 1.2439x; 1.0797x over previous
//
#include <hip/hip_runtime.h>

typedef unsigned short u16;
typedef __bf16 bf16x8 __attribute__((ext_vector_type(8)));
typedef float f32x4 __attribute__((ext_vector_type(4)));

__device__ __forceinline__ u16 f2bf(float f) {
  unsigned int u = __float_as_uint(f);
  u += 0x7fffu + ((u >> 16) & 1u);
  return (u16)(u >> 16);
}
__device__ __forceinline__ float bf2f(u16 v) {
  return __uint_as_float(((unsigned)v) << 16);
}

#define GLDS16(gp, lp)                                                   \
  __builtin_amdgcn_global_load_lds(                                      \
      (const __attribute__((address_space(1))) unsigned int*)(gp),       \
      (__attribute__((address_space(3))) unsigned int*)(lp), 16, 0, 0)

// B=8, C=256, L=4096, M=32768, NHEAD=8, dim=32
// ws layout (bytes)
#define OFF_WQ     0u
#define OFF_WK     131072u     /* wkvt rows 0:256 */
#define OFF_WV     262144u
#define OFF_WM     393216u
#define OFF_W1     524288u
#define OFF_W2     1048576u
#define OFF_CAT    1310720u    /* u16 [M][512]: 0:256 xs, 256:512 ln1 */
#define OFF_SSB    34865152u   /* u16 [M][256] ss_bf16 ; later Qs (Q*Z) */
#define OFF_KVPROJ 68419584u   /* u16 [M][512] K|vals bf16 ; later hidden */
#define OFF_KV     152305664u  /* f32 [64][32][32] */
#define OFF_KS     152567808u  /* f32 [64][32] */
#define OFF_KVP    152576000u  /* f32 [8][64][32][32] partials ; later wcomb */
#define OFF_KSP    154673152u  /* f32 [8][64][32] partials */

// ---- transposes fp32 [C,L] -> bf16 [L,C] ------------------------------------
__global__ __launch_bounds__(256) void transpose_in_kernel(
    const float* __restrict__ x, const float* __restrict__ srcp,
    u16* __restrict__ cat, u16* __restrict__ ssb) {
  __shared__ float s[32][33];
  int z = blockIdx.z;
  const float* src = z < 8 ? x : srcp;
  u16* dst = z < 8 ? cat : ssb;
  int dstride = z < 8 ? 512 : 256;
  int b = z & 7;
  int lt = blockIdx.x * 32, ct = blockIdx.y * 32;
  int tx = threadIdx.x & 31, ty = threadIdx.x >> 5;
#pragma unroll
  for (int i = 0; i < 4; ++i)
    s[ty + i * 8][tx] = src[((size_t)b * 256 + ct + ty + i * 8) * 4096 + lt + tx];
  __syncthreads();
#pragma unroll
  for (int i = 0; i < 4; ++i)
    dst[((size_t)b * 4096 + lt + ty + i * 8) * dstride + ct + tx] = f2bf(s[tx][ty + i * 8]);
}

// ---- weight prep: fp32 [K,N] -> bf16 [N,K], all weights one dispatch --------
__global__ __launch_bounds__(256) void wprep_all_kernel(
    const float* __restrict__ Wq, const float* __restrict__ Wk,
    const float* __restrict__ Wv, const float* __restrict__ Wm,
    const float* __restrict__ W1, const float* __restrict__ W2,
    u16* __restrict__ dq, u16* __restrict__ dk, u16* __restrict__ dv,
    u16* __restrict__ dm, u16* __restrict__ d1, u16* __restrict__ d2) {
  __shared__ float s[32][33];
  int bid = blockIdx.x;
  const float* src; u16* dst; int Kd, Nd, t;
  if (bid < 64)       { src = Wq; dst = dq; Kd = 256; Nd = 256; t = bid; }
  else if (bid < 128) { src = Wk; dst = dk; Kd = 256; Nd = 256; t = bid - 64; }
  else if (bid < 192) { src = Wv; dst = dv; Kd = 256; Nd = 256; t = bid - 128; }
  else if (bid < 256) { src = Wm; dst = dm; Kd = 256; Nd = 256; t = bid - 192; }
  else if (bid < 512) { src = W1; dst = d1; Kd = 512; Nd = 512; t = bid - 256; }
  else                { src = W2; dst = d2; Kd = 512; Nd = 256; t = bid - 512; }
  int ntn = Nd >> 5;
  int kt = (t / ntn) * 32, nt = (t % ntn) * 32;
  int tx = threadIdx.x & 31, ty = threadIdx.x >> 5;
#pragma unroll
  for (int i = 0; i < 4; ++i)
    s[ty + i * 8][tx] = src[(size_t)(kt + ty + i * 8) * Nd + nt + tx];
  __syncthreads();
#pragma unroll
  for (int i = 0; i < 4; ++i)
    dst[(size_t)(nt + ty + i * 8) * Kd + kt + tx] = f2bf(s[tx][ty + i * 8]);
}

// ---- bf16 MFMA GEMM, 128x128 tile, 4 waves, gload_lds staging ---------------
// EPI: 3 relu bf16 | 4 fused kv (col<256 elu+1, else /4096) bf16
// XS=1: linear grid 1024, XCD-chunked mapping (4 n-tiles per m-panel share XCD)
template <int EPI, int XS>
__global__ __launch_bounds__(256) void gemm_kernel(
    const u16* __restrict__ A, int lda, const u16* __restrict__ Wt, int K,
    u16* __restrict__ outp, int ldo) {
  __shared__ alignas(16) u16 sA[128 * 64];
  __shared__ alignas(16) u16 sB[128 * 64];
  const int tid = threadIdx.x;
  int m0, n0;
  if (XS) {
    int bid = blockIdx.x;
    int xcd = bid & 7, i = bid >> 3;
    m0 = (xcd * 32 + (i >> 2)) * 128;
    n0 = (i & 3) * 128;
  } else {
    m0 = blockIdx.y * 128;
    n0 = blockIdx.x * 128;
  }
  const int w = tid >> 6, lane = tid & 63;
  const int wm = (w >> 1) * 64, wn = (w & 1) * 64;
  const int lr = lane & 15, lk = lane >> 4;
  f32x4 acc[4][4] = {};
  const int srow = tid >> 3, sch = (tid & 7) << 3;
  const u16* ga = A + (size_t)(m0 + srow) * lda + sch;
  const u16* gb = Wt + (size_t)(n0 + srow) * K + sch;

  const int nkt = K >> 6;
  for (int kt = 0; kt < nkt; ++kt) {
    __syncthreads();
#pragma unroll
    for (int i = 0; i < 4; ++i) {
      GLDS16(ga + (size_t)i * 32 * lda + kt * 64, sA + (tid + i * 256) * 8);
      GLDS16(gb + (size_t)i * 32 * K + kt * 64, sB + (tid + i * 256) * 8);
    }
    __syncthreads();
    bf16x8 af[4][2], bfr[4][2];
#pragma unroll
    for (int f = 0; f < 4; ++f) {
#pragma unroll
      for (int ks = 0; ks < 2; ++ks) {
        af[f][ks] = *reinterpret_cast<const bf16x8*>(
            &sA[(wm + f * 16 + lr) * 64 + ks * 32 + lk * 8]);
        bfr[f][ks] = *reinterpret_cast<const bf16x8*>(
            &sB[(wn + f * 16 + lr) * 64 + ks * 32 + lk * 8]);
      }
    }
#pragma unroll
    for (int ks = 0; ks < 2; ++ks)
#pragma unroll
      for (int fm = 0; fm < 4; ++fm)
#pragma unroll
        for (int fn = 0; fn < 4; ++fn)
          acc[fm][fn] = __builtin_amdgcn_mfma_f32_16x16x32_bf16(
              af[fm][ks], bfr[fn][ks], acc[fm][fn], 0, 0, 0);
  }

  const int r0 = (lane >> 4) * 4, c0 = lane & 15;
#pragma unroll
  for (int fm = 0; fm < 4; ++fm) {
#pragma unroll
    for (int fn = 0; fn < 4; ++fn) {
      int gr = m0 + wm + fm * 16 + r0;
      int gc = n0 + wn + fn * 16 + c0;
#pragma unroll
      for (int r = 0; r < 4; ++r) {
        float v = acc[fm][fn][r];
        if (EPI == 3) v = v > 0.f ? v : 0.f;
        if (EPI == 4) v = (gc < 256) ? (v > 0.f ? v + 1.f : __expf(v)) : v * (1.f / 4096.f);
        outp[(size_t)(gr + r) * ldo + gc] = f2bf(v);
      }
    }
  }
}

// ---- KV partial over L-slices (reads bf16 kvproj [M][512]) ------------------
__global__ __launch_bounds__(256) void kv_partial_kernel(
    const u16* __restrict__ KVproj, float* __restrict__ KVp,
    float* __restrict__ KSp) {
  __shared__ alignas(16) float sK[64][32];
  __shared__ alignas(16) float sV[64][32];
  const int bh = blockIdx.x, sl = blockIdx.y;
  const int b = bh >> 3, h = bh & 7;
  const int t = threadIdx.x;
  const int lrow = t >> 2, lcol = (t & 3) * 8;
  const int d = t >> 3, vg = (t & 7) * 4;
  float a0 = 0, a1 = 0, a2 = 0, a3 = 0, ks = 0;
  for (int lt = 0; lt < 512; lt += 64) {
    __syncthreads();
    size_t roff = ((size_t)b * 4096 + sl * 512 + lt + lrow) * 512 + h * 32 + lcol;
    uint4 kq = *reinterpret_cast<const uint4*>(KVproj + roff);
    uint4 vq = *reinterpret_cast<const uint4*>(KVproj + roff + 256);
    float* dk = &sK[lrow][lcol];
    float* dv = &sV[lrow][lcol];
#pragma unroll
    for (int j = 0; j < 4; ++j) {
      unsigned uk = ((const unsigned*)&kq)[j];
      unsigned uv = ((const unsigned*)&vq)[j];
      dk[2 * j] = __uint_as_float(uk << 16);
      dk[2 * j + 1] = __uint_as_float(uk & 0xffff0000u);
      dv[2 * j] = __uint_as_float(uv << 16);
      dv[2 * j + 1] = __uint_as_float(uv & 0xffff0000u);
    }
    __syncthreads();
#pragma unroll 8
    for (int i = 0; i < 64; ++i) {
      float kd = sK[i][d];
      a0 += kd * sV[i][vg + 0];
      a1 += kd * sV[i][vg + 1];
      a2 += kd * sV[i][vg + 2];
      a3 += kd * sV[i][vg + 3];
      ks += kd;
    }
  }
  float* o = KVp + (size_t)sl * 65536 + bh * 1024 + d * 32 + vg;
  o[0] = a0; o[1] = a1; o[2] = a2; o[3] = a3;
  if ((t & 7) == 0) KSp[(size_t)sl * 2048 + bh * 32 + d] = ks;
}

__global__ __launch_bounds__(256) void kv_reduce_kernel(
    const float* __restrict__ KVp, const float* __restrict__ KSp,
    float* __restrict__ KV, float* __restrict__ Ksum) {
  int gid = blockIdx.x * 256 + threadIdx.x;
  if (gid < 65536) {
    float s = 0;
#pragma unroll
    for (int i = 0; i < 8; ++i) s += KVp[(size_t)i * 65536 + gid];
    KV[gid] = s;
  } else if (gid - 65536 < 2048) {
    int j = gid - 65536;
    float s = 0;
#pragma unroll
    for (int i = 0; i < 8; ++i) s += KSp[(size_t)i * 2048 + j];
    Ksum[j] = s;
  }
}

// ---- W_comb[b][n][k] = sum_v KV[b,h(k),d(k),v] * WmT[n][h*32+v] -> bf16 -----
__global__ __launch_bounds__(256) void wcomb_kernel(
    const float* __restrict__ KVb, const u16* __restrict__ wmt,
    u16* __restrict__ wc) {
  const int bid = blockIdx.x;  // 0..2047
  const int b = bid >> 8, n = bid & 255;
  const int k = threadIdx.x, h = k >> 5, d = k & 31;
  const float* kv = KVb + ((size_t)b * 8 + h) * 1024 + d * 32;
  const u16* wm = wmt + (size_t)n * 256 + h * 32;
  float s = 0.f;
#pragma unroll
  for (int v = 0; v < 32; ++v) s += kv[v] * bf2f(wm[v]);
  wc[((size_t)b * 256 + n) * 256 + k] = f2bf(s);
}

// ---- FUSED: Q projection + elu+1 + z-scale -> Qs bf16 -----------------------
// BM=128, N=256 full, K=256; grid 256, 512 threads (8 waves 2m x 4n)
__global__ __launch_bounds__(512) void qproj_fused_kernel(
    const u16* __restrict__ cat, const u16* __restrict__ WqT,
    const float* __restrict__ KSb, u16* __restrict__ Qs) {
  __shared__ alignas(16) u16 sA[128 * 64];
  __shared__ alignas(16) u16 sB[256 * 64];
  const int t = threadIdx.x;
  const int m0 = blockIdx.x * 128;
  const int b = m0 >> 12;
  const int w = t >> 6, lane = t & 63;
  const int wm = (w >> 2) * 64, wn = (w & 3) * 64;
  const int lr = lane & 15, lk = lane >> 4;
  f32x4 acc[4][4] = {};
  float ksv[4];
#pragma unroll
  for (int fn = 0; fn < 4; ++fn) ksv[fn] = KSb[b * 256 + wn + fn * 16 + lr];
  for (int kt = 0; kt < 4; ++kt) {
    __syncthreads();
#pragma unroll
    for (int i = 0; i < 2; ++i) {
      int id = t + i * 512, row = id >> 3, chn = (id & 7) << 3;
      GLDS16(cat + (size_t)(m0 + row) * 512 + kt * 64 + chn, sA + id * 8);
    }
#pragma unroll
    for (int i = 0; i < 4; ++i) {
      int id = t + i * 512, row = id >> 3, chn = (id & 7) << 3;
      GLDS16(WqT + (size_t)row * 256 + kt * 64 + chn, sB + id * 8);
    }
    __syncthreads();
    bf16x8 af[4][2], bfr[4][2];
#pragma unroll
    for (int f = 0; f < 4; ++f) {
#pragma unroll
      for (int ks = 0; ks < 2; ++ks) {
        af[f][ks] = *reinterpret_cast<const bf16x8*>(
            &sA[(wm + f * 16 + lr) * 64 + ks * 32 + lk * 8]);
        bfr[f][ks] = *reinterpret_cast<const bf16x8*>(
            &sB[(wn + f * 16 + lr) * 64 + ks * 32 + lk * 8]);
      }
    }
#pragma unroll
    for (int ks = 0; ks < 2; ++ks)
#pragma unroll
      for (int fm = 0; fm < 4; ++fm)
#pragma unroll
        for (int fn = 0; fn < 4; ++fn)
          acc[fm][fn] = __builtin_amdgcn_mfma_f32_16x16x32_bf16(
              af[fm][ks], bfr[fn][ks], acc[fm][fn], 0, 0, 0);
  }
  // epilogue: Q=elu+1; per-head z via 4x shfl_xor over lr bits; scale; store
#pragma unroll
  for (int fm = 0; fm < 4; ++fm)
#pragma unroll
    for (int r = 0; r < 4; ++r) {
      float q[4];
#pragma unroll
      for (int fn = 0; fn < 4; ++fn) {
        float v = acc[fm][fn][r];
        q[fn] = v > 0.f ? v + 1.f : __expf(v);
      }
      float zd0 = q[0] * ksv[0] + q[1] * ksv[1];
      float zd1 = q[2] * ksv[2] + q[3] * ksv[3];
#pragma unroll
      for (int off = 1; off < 16; off <<= 1) {
        zd0 += __shfl_xor(zd0, off);
        zd1 += __shfl_xor(zd1, off);
      }
      float z0 = 4096.f / (zd0 + 1e-6f);
      float z1 = 4096.f / (zd1 + 1e-6f);
      size_t row = (size_t)(m0 + wm + fm * 16 + lk * 4 + r) * 256;
      Qs[row + wn + lr] = f2bf(q[0] * z0);
      Qs[row + wn + 16 + lr] = f2bf(q[1] * z0);
      Qs[row + wn + 32 + lr] = f2bf(q[2] * z1);
      Qs[row + wn + 48 + lr] = f2bf(q[3] * z1);
    }
}

// ---- FUSED: msg = Qs @ Wcomb[b]  + LN1 -> cat[:,256:512] bf16 ---------------
__global__ __launch_bounds__(512) void msgwm_ln1_kernel(
    const u16* __restrict__ Qs, const u16* __restrict__ wc,
    const float* __restrict__ g1, const float* __restrict__ b1,
    u16* __restrict__ cat) {
  __shared__ alignas(16) char smem[49152 + 4096 + 2048];
  u16* sA = (u16*)smem;                   // [128][64]
  u16* sB = (u16*)(smem + 16384);         // [256][64]
  float* scr = (float*)(smem + 49152);    // [128][8]
  float* sG = (float*)(smem + 53248);     // g1|b1
  u16* T = (u16*)smem;                    // [64][264] overlay post-GEMM
  const int t = threadIdx.x;
  const int m0 = blockIdx.x * 128;
  const int b = m0 >> 12;
  const u16* Bw = wc + (size_t)b * 65536;
  if (t < 256) { sG[t] = g1[t]; sG[256 + t] = b1[t]; }
  const int w = t >> 6, lane = t & 63;
  const int wm = (w >> 2) * 64, wn = (w & 3) * 64;
  const int lr = lane & 15, lk = lane >> 4;
  f32x4 acc[4][4] = {};
  for (int kt = 0; kt < 4; ++kt) {
    __syncthreads();
#pragma unroll
    for (int i = 0; i < 2; ++i) {
      int id = t + i * 512, row = id >> 3, chn = (id & 7) << 3;
      GLDS16(Qs + (size_t)(m0 + row) * 256 + kt * 64 + chn, sA + id * 8);
    }
#pragma unroll
    for (int i = 0; i < 4; ++i) {
      int id = t + i * 512, row = id >> 3, chn = (id & 7) << 3;
      GLDS16(Bw + (size_t)row * 256 + kt * 64 + chn, sB + id * 8);
    }
    __syncthreads();
    bf16x8 af[4][2], bfr[4][2];
#pragma unroll
    for (int f = 0; f < 4; ++f) {
#pragma unroll
      for (int ks = 0; ks < 2; ++ks) {
        af[f][ks] = *reinterpret_cast<const bf16x8*>(
            &sA[(wm + f * 16 + lr) * 64 + ks * 32 + lk * 8]);
        bfr[f][ks] = *reinterpret_cast<const bf16x8*>(
            &sB[(wn + f * 16 + lr) * 64 + ks * 32 + lk * 8]);
      }
    }
#pragma unroll
    for (int ks = 0; ks < 2; ++ks)
#pragma unroll
      for (int fm = 0; fm < 4; ++fm)
#pragma unroll
        for (int fn = 0; fn < 4; ++fn)
          acc[fm][fn] = __builtin_amdgcn_mfma_f32_16x16x32_bf16(
              af[fm][ks], bfr[fn][ks], acc[fm][fn], 0, 0, 0);
  }
  // ---- LN1 cross-wave ----
#pragma unroll
  for (int fm = 0; fm < 4; ++fm)
#pragma unroll
    for (int r = 0; r < 4; ++r) {
      float s = 0.f, sq = 0.f;
#pragma unroll
      for (int fn = 0; fn < 4; ++fn) {
        float a = acc[fm][fn][r];
        s += a; sq += a * a;
      }
#pragma unroll
      for (int off = 1; off < 16; off <<= 1) {
        s += __shfl_xor(s, off);
        sq += __shfl_xor(sq, off);
      }
      if (lr == 0) {
        int row = wm + fm * 16 + lk * 4 + r;
        scr[row * 8 + (w & 3) * 2] = s;
        scr[row * 8 + (w & 3) * 2 + 1] = sq;
      }
    }
  __syncthreads();
  float gvs[4], bvs[4];
#pragma unroll
  for (int fn = 0; fn < 4; ++fn) {
    gvs[fn] = sG[wn + fn * 16 + lr];
    bvs[fn] = sG[256 + wn + fn * 16 + lr];
  }
#pragma unroll
  for (int fm = 0; fm < 4; ++fm)
#pragma unroll
    for (int r = 0; r < 4; ++r) {
      int row = wm + fm * 16 + lk * 4 + r;
      float s = 0.f, sq = 0.f;
#pragma unroll
      for (int j = 0; j < 4; ++j) {
        s += scr[row * 8 + j * 2];
        sq += scr[row * 8 + j * 2 + 1];
      }
      float mu = s * (1.f / 256.f);
      float var = sq * (1.f / 256.f) - mu * mu;
      float rstd = rsqrtf(var + 1e-5f);
#pragma unroll
      for (int fn = 0; fn < 4; ++fn)
        acc[fm][fn][r] = (acc[fm][fn][r] - mu) * rstd * gvs[fn] + bvs[fn];
    }
  // ---- restage through LDS, coalesced bf16 store to cat[:,256:512] ----
  for (int hh = 0; hh < 2; ++hh) {
    __syncthreads();
    if ((w >> 2) == hh) {
#pragma unroll
      for (int fm = 0; fm < 4; ++fm)
#pragma unroll
        for (int fn = 0; fn < 4; ++fn)
#pragma unroll
          for (int r = 0; r < 4; ++r)
            T[(fm * 16 + lk * 4 + r) * 264 + wn + fn * 16 + lr] =
                f2bf(acc[fm][fn][r]);
    }
    __syncthreads();
#pragma unroll
    for (int i = 0; i < 4; ++i) {
      int idx = t + i * 512;
      int row = idx >> 5, c16 = idx & 31;
      uint4 val = *reinterpret_cast<const uint4*>(&T[row * 264 + c16 * 8]);
      *reinterpret_cast<uint4*>(
          cat + (size_t)(m0 + hh * 64 + row) * 512 + 256 + c16 * 8) = val;
    }
  }
}

// ---- FUSED: MLP2 + LN2 + bf16-residual + transpose -> out -------------------
__global__ __launch_bounds__(512) void mlp2_tail_kernel(
    const u16* __restrict__ hidden, const u16* __restrict__ W2T,
    const float* __restrict__ g2, const float* __restrict__ b2,
    const u16* __restrict__ catp, float* __restrict__ out) {
  __shared__ alignas(16) char smem[16384 + 32768 + 4096 + 2048];
  u16* sA = (u16*)smem;                   // [128][64]
  u16* sB = (u16*)(smem + 16384);         // [256][64]
  float* scr = (float*)(smem + 49152);    // [128][8]
  float* sG = (float*)(smem + 53248);     // g2|b2
  float* T = (float*)smem;                // [64][129] overlay, post-GEMM
  const int t = threadIdx.x;
  const int m0 = blockIdx.x * 128;
  const int b = m0 >> 12, l0 = m0 & 4095;
  if (t < 256) { sG[t] = g2[t]; sG[256 + t] = b2[t]; }
  const int w = t >> 6, lane = t & 63;
  const int wm = (w >> 2) * 64, wn = (w & 3) * 64;
  const int lr = lane & 15, lk = lane >> 4;
  f32x4 acc[4][4] = {};
  for (int kt = 0; kt < 8; ++kt) {
    __syncthreads();
#pragma unroll
    for (int i = 0; i < 2; ++i) {
      int id = t + i * 512, row = id >> 3, chn = (id & 7) << 3;
      GLDS16(hidden + (size_t)(m0 + row) * 512 + kt * 64 + chn, sA + id * 8);
    }
#pragma unroll
    for (int i = 0; i < 4; ++i) {
      int id = t + i * 512, row = id >> 3, chn = (id & 7) << 3;
      GLDS16(W2T + (size_t)row * 512 + kt * 64 + chn, sB + id * 8);
    }
    __syncthreads();
    bf16x8 af[4][2], bfr[4][2];
#pragma unroll
    for (int f = 0; f < 4; ++f) {
#pragma unroll
      for (int ks = 0; ks < 2; ++ks) {
        af[f][ks] = *reinterpret_cast<const bf16x8*>(
            &sA[(wm + f * 16 + lr) * 64 + ks * 32 + lk * 8]);
        bfr[f][ks] = *reinterpret_cast<const bf16x8*>(
            &sB[(wn + f * 16 + lr) * 64 + ks * 32 + lk * 8]);
      }
    }
#pragma unroll
    for (int ks = 0; ks < 2; ++ks)
#pragma unroll
      for (int fm = 0; fm < 4; ++fm)
#pragma unroll
        for (int fn = 0; fn < 4; ++fn)
          acc[fm][fn] = __builtin_amdgcn_mfma_f32_16x16x32_bf16(
              af[fm][ks], bfr[fn][ks], acc[fm][fn], 0, 0, 0);
  }
  // ---- LN2 cross-wave ----
#pragma unroll
  for (int fm = 0; fm < 4; ++fm)
#pragma unroll
    for (int r = 0; r < 4; ++r) {
      float s = 0.f, sq = 0.f;
#pragma unroll
      for (int fn = 0; fn < 4; ++fn) {
        float a = acc[fm][fn][r];
        s += a; sq += a * a;
      }
#pragma unroll
      for (int off = 1; off < 16; off <<= 1) {
        s += __shfl_xor(s, off);
        sq += __shfl_xor(sq, off);
      }
      if (lr == 0) {
        int row = wm + fm * 16 + lk * 4 + r;
        scr[row * 8 + (w & 3) * 2] = s;
        scr[row * 8 + (w & 3) * 2 + 1] = sq;
      }
    }
  __syncthreads();
  float gvs[4], bvs[4];
#pragma unroll
  for (int fn = 0; fn < 4; ++fn) {
    gvs[fn] = sG[wn + fn * 16 + lr];
    bvs[fn] = sG[256 + wn + fn * 16 + lr];
  }
#pragma unroll
  for (int fm = 0; fm < 4; ++fm)
#pragma unroll
    for (int r = 0; r < 4; ++r) {
      int row = wm + fm * 16 + lk * 4 + r;
      float s = 0.f, sq = 0.f;
#pragma unroll
      for (int j = 0; j < 4; ++j) {
        s += scr[row * 8 + j * 2];
        sq += scr[row * 8 + j * 2 + 1];
      }
      float mu = s * (1.f / 256.f);
      float var = sq * (1.f / 256.f) - mu * mu;
      float rstd = rsqrtf(var + 1e-5f);
#pragma unroll
      for (int fn = 0; fn < 4; ++fn) {
        float xs = bf2f(catp[(size_t)(m0 + row) * 512 + wn + fn * 16 + lr]);
        acc[fm][fn][r] = (acc[fm][fn][r] - mu) * rstd * gvs[fn] + bvs[fn] + xs;
      }
    }
  __syncthreads();
  // ---- transpose chunks of 64 cols, pure coalesced write ----
  for (int cc = 0; cc < 4; ++cc) {
    if ((w & 3) == cc) {
#pragma unroll
      for (int fm = 0; fm < 4; ++fm)
#pragma unroll
        for (int fn = 0; fn < 4; ++fn)
#pragma unroll
          for (int r = 0; r < 4; ++r)
            T[(fn * 16 + lr) * 129 + wm + fm * 16 + lk * 4 + r] = acc[fm][fn][r];
    }
    __syncthreads();
#pragma unroll
    for (int i = 0; i < 4; ++i) {
      int idx = t + i * 512;
      int cT = idx >> 5, lq = (idx & 31) * 4;
      int cg = cc * 64 + cT;
      size_t o = ((size_t)b * 256 + cg) * 4096 + l0 + lq;
      float4 ov;
      ov.x = T[cT * 129 + lq];
      ov.y = T[cT * 129 + lq + 1];
      ov.z = T[cT * 129 + lq + 2];
      ov.w = T[cT * 129 + lq + 3];
      *reinterpret_cast<float4*>(out + o) = ov;
    }
    __syncthreads();
  }
}

extern "C" void kernel_launch(void* const* d_in, const int* in_sizes, int n_in,
                              void* d_out, int out_size, void* d_ws, size_t ws_size,
                              hipStream_t stream) {
  (void)in_sizes; (void)n_in; (void)out_size; (void)ws_size;
  const float* x = (const float*)d_in[0];
  const float* srcp = (const float*)d_in[1];
  const float* Wq = (const float*)d_in[2];
  const float* Wk = (const float*)d_in[3];
  const float* Wv = (const float*)d_in[4];
  const float* Wm = (const float*)d_in[5];
  const float* W1 = (const float*)d_in[6];
  const float* W2 = (const float*)d_in[7];
  const float* g1 = (const float*)d_in[8];
  const float* b1 = (const float*)d_in[9];
  const float* g2 = (const float*)d_in[10];
  const float* b2 = (const float*)d_in[11];
  float* out = (float*)d_out;
  char* ws = (char*)d_ws;

  u16* wqt = (u16*)(ws + OFF_WQ);
  u16* wkvt = (u16*)(ws + OFF_WK);
  u16* wkt = (u16*)(ws + OFF_WK);
  u16* wvt = (u16*)(ws + OFF_WV);
  u16* wmt = (u16*)(ws + OFF_WM);
  u16* w1t = (u16*)(ws + OFF_W1);
  u16* w2t = (u16*)(ws + OFF_W2);
  u16* cat = (u16*)(ws + OFF_CAT);
  u16* ssb = (u16*)(ws + OFF_SSB);
  u16* kvproj = (u16*)(ws + OFF_KVPROJ);
  float* KVb = (float*)(ws + OFF_KV);
  float* KSb = (float*)(ws + OFF_KS);
  float* KVp = (float*)(ws + OFF_KVP);
  float* KSp = (float*)(ws + OFF_KSP);
  u16* hidden = kvproj;      // reuse after kv_partial consumed kvproj
  u16* Qs = ssb;             // reuse after kv gemm consumed ssb
  u16* wcombT = (u16*)(ws + OFF_KVP);  // reuse partials after kv_reduce

  dim3 blk(256);
  wprep_all_kernel<<<dim3(640), blk, 0, stream>>>(Wq, Wk, Wv, Wm, W1, W2,
                                                  wqt, wkt, wvt, wmt, w1t, w2t);
  transpose_in_kernel<<<dim3(128, 8, 16), blk, 0, stream>>>(x, srcp, cat, ssb);
  gemm_kernel<4, 1><<<dim3(1024), blk, 0, stream>>>(ssb, 256, wkvt, 256, kvproj, 512);
  kv_partial_kernel<<<dim3(64, 8), blk, 0, stream>>>(kvproj, KVp, KSp);
  kv_reduce_kernel<<<dim3(264), blk, 0, stream>>>(KVp, KSp, KVb, KSb);
  qproj_fused_kernel<<<dim3(256), dim3(512), 0, stream>>>(cat, wqt, KSb, Qs);
  wcomb_kernel<<<dim3(2048), blk, 0, stream>>>(KVb, wmt, wcombT);
  msgwm_ln1_kernel<<<dim3(256), dim3(512), 0, stream>>>(Qs, wcombT, g1, b1, cat);
  gemm_kernel<3, 1><<<dim3(1024), blk, 0, stream>>>(cat, 512, w1t, 512, hidden, 512);
  mlp2_tail_kernel<<<dim3(256), dim3(512), 0, stream>>>(hidden, w2t, g2, b2, cat, out);
}